// Round 1
// 422.797 us; speedup vs baseline: 1.1171x; 1.1171x over previous
//
#include <hip/hip_runtime.h>
#include <math.h>

static constexpr int NB = 32;
static constexpr int ND = 128;

typedef short bf16x8 __attribute__((ext_vector_type(8)));
typedef float f32x4  __attribute__((ext_vector_type(4)));
typedef unsigned short u16x8 __attribute__((ext_vector_type(8)));

__device__ __forceinline__ float lrelu(float x){ return x > 0.f ? x : 0.2f*x; }
__device__ __forceinline__ unsigned short f2b(float f){
  unsigned u = __float_as_uint(f);
  return (unsigned short)((u + 0x7FFFu + ((u>>16)&1u)) >> 16);
}
__device__ __forceinline__ float b2f(unsigned short b){
  return __uint_as_float(((unsigned)b) << 16);
}

// ---- fold v[k][h] = sum_j W[k][h*32+j]*a[h*32+j] for all (layer, liverel, role) ----
__global__ __launch_bounds__(128) void k_fold(const float* __restrict__ Wsrc,
    const float* __restrict__ Wdst, const float* __restrict__ asrc,
    const float* __restrict__ adst, float* __restrict__ vbuf){
  const int wid[5] = {0,1,3,5,6};
  int lr = blockIdx.x, role = blockIdx.y, l = blockIdx.z;
  int r = wid[lr];
  const float* W = (role ? Wdst : Wsrc) + (size_t)(l*8+r)*16384;
  const float* a = (role ? adst : asrc) + (size_t)(l*8+r)*128;
  int k = threadIdx.x;
  float* o = vbuf + ((size_t)((l*5+lr)*2+role))*512 + k*4;
  #pragma unroll
  for(int h=0;h<4;h++){
    float s = 0.f;
    #pragma unroll
    for(int j=0;j<32;j++) s += W[k*128 + h*32 + j]*a[h*32 + j];
    o[h] = s;
  }
}

// ---- pre-pack W_src (5 live rels x 2 layers) into bf16 MFMA B-fragment layout ----
__global__ __launch_bounds__(256) void k_wpack(const float* __restrict__ Wsrc,
    unsigned short* __restrict__ Wf){
  const int wid[5] = {0,1,3,5,6};
  int lr = blockIdx.x, l = blockIdx.y;
  const float* W = Wsrc + (size_t)(l*8+wid[lr])*16384;
  unsigned short* o = Wf + (size_t)((l*5+lr)*4)*4096;
  for(int idx=threadIdx.x; idx<128*128; idx+=256){
    int k = idx >> 7, col = idx & 127;
    int h = col >> 5, cc = col & 31;
    int k4 = k>>2, g = k4&3, kk = k4>>3, j = 4*((k4>>2)&1) + (k&3);
    int nb = cc>>4, lane = (cc&15) + 16*g;
    o[(size_t)h*4096 + ((size_t)((kk*2+nb)*64 + lane))*8 + j] = f2b(W[k*128 + col]);
  }
}

// ---- convert fp32 inputs (ct,pet,gen) -> bf16 ----
__global__ __launch_bounds__(256) void k_conv(const float* __restrict__ i0,
    const float* __restrict__ i1, const float* __restrict__ i2,
    unsigned short* __restrict__ x16){
  int bx = blockIdx.x;
  const float* src; size_t base; unsigned short* dst;
  if(bx < 2048){ src=i0; base=(size_t)bx*2048; dst=x16; }
  else if(bx < 4096){ src=i1; base=(size_t)(bx-2048)*2048; dst=x16+4194304; }
  else { src=i2; base=(size_t)(bx-4096)*2048; dst=x16+8388608; }
  size_t o = base + (size_t)threadIdx.x*8;
  float4 a = *(const float4*)(src+o), b = *(const float4*)(src+o+4);
  u16x8 r;
  r[0]=f2b(a.x); r[1]=f2b(a.y); r[2]=f2b(a.z); r[3]=f2b(a.w);
  r[4]=f2b(b.x); r[5]=f2b(b.y); r[6]=f2b(b.z); r[7]=f2b(b.w);
  *(u16x8*)(dst+o) = r;
}

// ================= fused CSR build: count+scan+fill in ONE kernel via LDS =================
struct CsrP {
  const int* eg[5];
  int l2E[5];
  int Nd_[5];
  int roff_[5];
  int eoff_[5];
};

__global__ __launch_bounds__(512) void k_csr(CsrP P, int* __restrict__ rowstart,
                                             int* __restrict__ srcidx){
  int b = blockIdx.x, r = blockIdx.y, t = threadIdx.x;
  int E = 1<<P.l2E[r], Nd = P.Nd_[r];
  const int* eg = P.eg[r] + (size_t)b*2*E;
  int* rsO = rowstart + P.roff_[r] + b*(Nd+1);
  int* siO = srcidx + P.eoff_[r] + (size_t)b*E;
  __shared__ int cnt[2048];
  __shared__ int stmp[512];
  for(int i=t;i<Nd;i+=512) cnt[i]=0;
  __syncthreads();
  for(int e=t;e<E;e+=512) atomicAdd(&cnt[eg[E+e]], 1);
  __syncthreads();
  int carry=0;
  for(int c0=0;c0<Nd;c0+=512){
    int idx=c0+t;
    int v=(idx<Nd)?cnt[idx]:0;
    stmp[t]=v; __syncthreads();
    for(int off=1;off<512;off<<=1){
      int u=(t>=off)?stmp[t-off]:0;
      __syncthreads();
      stmp[t]+=u;
      __syncthreads();
    }
    int excl=stmp[t]-v+carry;
    if(idx<Nd){ rsO[idx]=excl; cnt[idx]=excl; }
    int tot = stmp[511];
    __syncthreads();
    carry+=tot;
  }
  if(t==0) rsO[Nd]=carry;
  __syncthreads();
  for(int e=t;e<E;e+=512){
    int src=eg[e], dst=eg[E+e];
    int pos=atomicAdd(&cnt[dst],1);
    siO[pos]=src;
  }
}

// ================= attention logits al_s/al_d via folded vectors =================
struct AlP {
  const float* xf[3];
  const unsigned short* xh[3];
  int useh;
  int boff[4];
  int nv[3];
  int vidx[3][4];
  unsigned long long ooff[3][4];
};

__global__ __launch_bounds__(256) void k_al(AlP P, const float* __restrict__ vl,
    float* __restrict__ albase){
  __shared__ float xl[64*129];
  __shared__ float sv[2048];
  int blk = blockIdx.x, tid = threadIdx.x;
  int t=0; while(t<2 && blk>=P.boff[t+1]) t++;
  int node0 = (blk - P.boff[t])*64;
  int nv = P.nv[t];
  for(int i=tid;i<nv*512;i+=256){ int q=i>>9, j=i&511; sv[i] = vl[P.vidx[t][q]*512 + j]; }
  if(P.useh){
    const unsigned short* xb = P.xh[t];
    #pragma unroll
    for(int i=0;i<4;i++){
      int flat = tid + i*256;
      int row = flat>>4, c8 = flat&15;
      u16x8 v8 = *(const u16x8*)(xb + ((size_t)(node0+row)*128 + c8*8));
      #pragma unroll
      for(int j=0;j<8;j++) xl[row*129 + c8*8 + j] = b2f((unsigned short)v8[j]);
    }
  } else {
    const float* xf = P.xf[t];
    #pragma unroll
    for(int i=0;i<8;i++){
      int flat = tid + i*256;
      int row = flat>>5, c4 = flat&31;
      float4 v = *(const float4*)(xf + ((size_t)(node0+row)*128 + c4*4));
      xl[row*129+c4*4+0]=v.x; xl[row*129+c4*4+1]=v.y;
      xl[row*129+c4*4+2]=v.z; xl[row*129+c4*4+3]=v.w;
    }
  }
  __syncthreads();
  int node = tid>>2, h = tid&3;
  for(int q=0;q<nv;q++){
    const float* vv = &sv[q*512];
    float s = 0.f;
    #pragma unroll 8
    for(int k=0;k<128;k++) s += xl[node*129+k]*vv[k*4+h];
    albase[P.ooff[t][q] + (size_t)(node0+node)*4 + h] = s;
  }
}

// ================= NEW: dense hs = x @ W_src per relation (bf16 MFMA) =================
// Block: 256 thr = 4 waves, 16 rows of one (b, type). ct/pet tiles compute 2 W's (self + ->gen).
struct HsP {
  int tb[4];
  unsigned long long xoff[3];
  int Ns[3];
  int nW[3];
  unsigned long long wfo[3][2];
  unsigned long long hso[3][2];
};

__global__ __launch_bounds__(256) void k_hs(HsP P, const unsigned short* __restrict__ x16,
    const unsigned short* __restrict__ Wf, unsigned short* __restrict__ hs){
  __shared__ unsigned short xl[16*132];
  int B = blockIdx.x;
  int t=0; while(t<2 && B>=P.tb[t+1]) t++;
  int local = B - P.tb[t];
  int b = local & 31, tile = local >> 5;
  int n0 = tile*16;
  int tid = threadIdx.x, w = tid>>6, ln = tid&63;
  {
    int row = tid>>4, ch = tid&15;
    u16x8 v = *(const u16x8*)(x16 + P.xoff[t] + ((size_t)((size_t)b*P.Ns[t] + n0+row)*128 + ch*8));
    *(u16x8*)&xl[row*132 + ch*8] = v;
  }
  __syncthreads();
  int g = ln>>4, r15 = ln&15;
  for(int rep=0; rep<P.nW[t]; rep++){
    const unsigned short* wf = Wf + P.wfo[t][rep] + (size_t)w*4096;
    f32x4 acc[2]; acc[0]=(f32x4){0,0,0,0}; acc[1]=(f32x4){0,0,0,0};
    #pragma unroll
    for(int kk=0;kk<4;kk++){
      const unsigned short* pa = &xl[r15*132 + kk*32 + 4*g];
      ushort4 lo = *(const ushort4*)pa;
      ushort4 hi = *(const ushort4*)(pa+16);
      union { ushort u[8]; bf16x8 v; } tmp;
      tmp.u[0]=lo.x; tmp.u[1]=lo.y; tmp.u[2]=lo.z; tmp.u[3]=lo.w;
      tmp.u[4]=hi.x; tmp.u[5]=hi.y; tmp.u[6]=hi.z; tmp.u[7]=hi.w;
      bf16x8 af = tmp.v;
      #pragma unroll
      for(int nb=0;nb<2;nb++){
        bf16x8 bw = *(const bf16x8*)(wf + ((size_t)((kk*2+nb)*64 + ln))*8);
        acc[nb] = __builtin_amdgcn_mfma_f32_16x16x32_bf16(af, bw, acc[nb], 0, 0, 0);
      }
    }
    unsigned short* ho = hs + P.hso[t][rep] + ((size_t)b*P.Ns[t] + n0)*128;
    #pragma unroll
    for(int qq=0;qq<4;qq++){
      int m = 4*g + qq;
      #pragma unroll
      for(int nb=0;nb<2;nb++){
        ho[(size_t)m*128 + w*32 + nb*16 + r15] = f2b(acc[nb][qq]);
      }
    }
  }
}

// ========= NEW fused kernel: softmax weights + weighted gather of hs (output space) =========
// One launch per layer, grid concat over {gen, ct, pet}. Block: 256 thr, 16 dsts.
// Per edge per lane: 1 dword gather + 2 fma (vs old 8 fma + agg round-trip + MFMA).
static constexpr int MAXE = 320;   // tile edges: mean 128, sigma ~11 -> 17 sigma headroom
static constexpr int WST  = 328;   // head-major wlds stride (328 mod 32 = 8 -> banks staggered)

struct Fu3P {
  int tboff[4];
  int nrel[3], ndshift[3];
  int roff[3][3], eoff[3][3], E[3][3], Ns[3][3];
  unsigned long long aoff[3][3], aldo[3][3];
  unsigned long long hoff[3][3];
  unsigned long long outoff[3];
};

__global__ __launch_bounds__(256, 8) void k_fuse3(Fu3P P,
    const int* __restrict__ rowstart, const int* __restrict__ srcidx,
    const float* __restrict__ als, const float* __restrict__ ald,
    const unsigned short* __restrict__ hs, unsigned short* __restrict__ out16){
  __shared__ float wlds[4*WST];   // logits/weights, head-major
  __shared__ int   silds[MAXE];
  __shared__ int   dlds[MAXE];
  int B = blockIdx.x;
  int t=0; while(t<2 && B>=P.tboff[t+1]) t++;
  int local = B - P.tboff[t];
  int b = local & 31, dtile = local >> 5;
  int Nd = 1 << P.ndshift[t];
  int d0 = dtile * 16;
  int tid = threadIdx.x, w = tid>>6, ln = tid&63;
  int h = ln>>4;
  float accA[4], accB[4];
  #pragma unroll
  for(int i=0;i<4;i++){ accA[i]=0.f; accB[i]=0.f; }
  for(int q=0;q<P.nrel[t];q++){
    const int* rs = rowstart + P.roff[t][q] + b*(Nd+1);
    const int* si = srcidx + P.eoff[t][q] + (size_t)b*P.E[t][q];
    const float* alsb = als + P.aoff[t][q] + (size_t)b*P.Ns[t][q]*4;
    const float* aldb = ald + P.aldo[t][q] + (size_t)b*(size_t)Nd*4;
    const unsigned short* hb = hs + P.hoff[t][q] + (size_t)b*P.Ns[t][q]*128;
    int ebase = rs[d0];
    int ecnt  = rs[d0+16] - ebase;
    // ---- pass0: stage src indices + per-edge dst-local index ----
    for(int e=tid; e<ecnt; e+=256) silds[e] = si[ebase + e];
    if(tid < 64){
      int dloc = tid>>2, j = tid&3;
      int e0 = rs[d0+dloc] - ebase, e1 = rs[d0+dloc+1] - ebase;
      for(int e=e0+j; e<e1; e+=4) dlds[e] = dloc;
    }
    __syncthreads();
    // ---- pass1: per-edge logits, all 4 heads from ONE float4 als load (L1-resident) ----
    for(int e=tid; e<ecnt; e+=256){
      int s = silds[e];
      int dloc = dlds[e];
      float4 as4 = *(const float4*)(alsb + (size_t)s*4);
      float4 ad4 = *(const float4*)(aldb + (size_t)(d0+dloc)*4);
      wlds[0*WST + e] = lrelu(as4.x + ad4.x);
      wlds[1*WST + e] = lrelu(as4.y + ad4.y);
      wlds[2*WST + e] = lrelu(as4.z + ad4.z);
      wlds[3*WST + e] = lrelu(as4.w + ad4.w);
    }
    __syncthreads();
    // ---- pass2: per (dloc,h): softmax over the dst's edges (LDS only) ----
    {
      int p = tid>>2, j = tid&3;
      int dloc = p>>2, hh = p&3;
      int e0 = rs[d0+dloc] - ebase, e1 = rs[d0+dloc+1] - ebase;
      float* wrow = &wlds[hh*WST];
      float m = -1e30f;
      for(int e=e0+j; e<e1; e+=4) m = fmaxf(m, wrow[e]);
      m = fmaxf(m, __shfl_xor(m,1));
      m = fmaxf(m, __shfl_xor(m,2));
      float den = 0.f;
      for(int e=e0+j; e<e1; e+=4){
        float pexp = __expf(wrow[e] - m);
        wrow[e] = pexp;
        den += pexp;
      }
      den += __shfl_xor(den,1);
      den += __shfl_xor(den,2);
      float inv = 1.f/(den + 1e-16f);
      for(int e=e0+j; e<e1; e+=4) wrow[e] *= inv;
    }
    __syncthreads();
    // ---- pass3: weighted gather of hs rows directly into output accumulators ----
    #pragma unroll
    for(int it=0; it<4; it++){
      int dloc = w*4 + it;
      int e0 = rs[d0+dloc] - ebase, e1 = rs[d0+dloc+1] - ebase;
      float a0 = 0.f, a1 = 0.f;
      int e = e0;
      int eal = (e0+3)&~3; if(eal > e1) eal = e1;
      for(; e<eal; e++){
        float wv = wlds[h*WST + e];
        unsigned v = *(const unsigned*)(hb + ((size_t)silds[e]*128 + 2*ln));
        a0 += wv*__uint_as_float(v<<16);
        a1 += wv*__uint_as_float(v&0xFFFF0000u);
      }
      for(; e+4<=e1; e+=4){
        int4  sq = *(const int4*)&silds[e];
        float4 wq = *(const float4*)&wlds[h*WST + e];
        unsigned v0 = *(const unsigned*)(hb + ((size_t)sq.x*128 + 2*ln));
        unsigned v1 = *(const unsigned*)(hb + ((size_t)sq.y*128 + 2*ln));
        unsigned v2 = *(const unsigned*)(hb + ((size_t)sq.z*128 + 2*ln));
        unsigned v3 = *(const unsigned*)(hb + ((size_t)sq.w*128 + 2*ln));
        a0 += wq.x*__uint_as_float(v0<<16); a1 += wq.x*__uint_as_float(v0&0xFFFF0000u);
        a0 += wq.y*__uint_as_float(v1<<16); a1 += wq.y*__uint_as_float(v1&0xFFFF0000u);
        a0 += wq.z*__uint_as_float(v2<<16); a1 += wq.z*__uint_as_float(v2&0xFFFF0000u);
        a0 += wq.w*__uint_as_float(v3<<16); a1 += wq.w*__uint_as_float(v3&0xFFFF0000u);
      }
      for(; e<e1; e++){
        float wv = wlds[h*WST + e];
        unsigned v = *(const unsigned*)(hb + ((size_t)silds[e]*128 + 2*ln));
        a0 += wv*__uint_as_float(v<<16);
        a1 += wv*__uint_as_float(v&0xFFFF0000u);
      }
      accA[it] += a0; accB[it] += a1;
    }
    __syncthreads();
  }
  // ---- epilogue: ELU + bf16 store ----
  #pragma unroll
  for(int it=0; it<4; it++){
    int m = d0 + w*4 + it;
    float v0 = accA[it], v1 = accB[it];
    v0 = v0 > 0.f ? v0 : expm1f(v0);
    v1 = v1 > 0.f ? v1 : expm1f(v1);
    ushort2 o; o.x = f2b(v0); o.y = f2b(v1);
    *(ushort2*)(out16 + P.outoff[t] + ((size_t)b*Nd + m)*128 + 2*ln) = o;
  }
}

// ================= pooling (3 pools batched via blockIdx.z; bf16 features) =================
__device__ __constant__ const size_t POFF[3] = {0ull, 4194304ull, 8388608ull};
__device__ __constant__ const int    PNN[3]  = {1024, 1024, 2048};
static constexpr int PCH = 64;
static constexpr int MAXCH = 32;

__global__ __launch_bounds__(128) void k_pool_psum(const unsigned short* __restrict__ x2,
    float* __restrict__ part){
  int p = blockIdx.z, b = blockIdx.x, c = blockIdx.y, t = threadIdx.x;
  int Nn = PNN[p];
  if(c*PCH >= Nn) return;
  const unsigned short* f = x2 + POFF[p] + ((size_t)b*Nn + c*PCH)*ND;
  float acc = 0.f;
  #pragma unroll 8
  for(int n=0;n<PCH;n++) acc += b2f(f[(size_t)n*ND + t]);
  part[(((size_t)p*NB + b)*MAXCH + c)*ND + t] = acc;
}

__global__ __launch_bounds__(128) void k_pool_q(const float* __restrict__ part,
    const float* __restrict__ Wp, const float* __restrict__ bp,
    float* __restrict__ q){
  int p = blockIdx.z, b = blockIdx.x, t = threadIdx.x;
  int nch = PNN[p]/PCH;
  __shared__ float mean[ND];
  float s = 0.f;
  for(int c=0;c<nch;c++) s += part[(((size_t)p*NB + b)*MAXCH + c)*ND + t];
  mean[t] = s / (float)PNN[p];
  __syncthreads();
  const float* W = Wp + (size_t)p*ND*ND;
  float qv = bp[p*ND + t];
  #pragma unroll 8
  for(int k=0;k<ND;k++) qv += mean[k]*W[k*ND + t];
  q[((size_t)p*NB + b)*ND + t] = qv;
}

__global__ __launch_bounds__(256) void k_pool_score(const unsigned short* __restrict__ x2,
    const float* __restrict__ q, float* __restrict__ sc){
  int p = blockIdx.z, b = blockIdx.y;
  int w = threadIdx.x >> 6, lane = threadIdx.x & 63;
  int n = blockIdx.x*4 + w;
  int Nn = PNN[p];
  if(n >= Nn) return;
  const unsigned short* f  = x2 + POFF[p] + ((size_t)b*Nn + n)*ND;
  const float* qb = q + ((size_t)p*NB + b)*ND;
  float s = b2f(f[lane])*qb[lane] + b2f(f[lane+64])*qb[lane+64];
  #pragma unroll
  for(int off=32; off; off>>=1) s += __shfl_xor(s, off);
  if(lane == 0) sc[((size_t)p*NB + b)*2048 + n] = s;
}

__global__ __launch_bounds__(256) void k_pool_smax(const float* __restrict__ sc,
    float* __restrict__ stat){
  int p = blockIdx.z, b = blockIdx.x, t = threadIdx.x;
  int Nn = PNN[p];
  __shared__ float red[256];
  const float* s = sc + ((size_t)p*NB + b)*2048;
  float mx = -1e30f;
  for(int n=t;n<Nn;n+=256) mx = fmaxf(mx, s[n]);
  red[t] = mx; __syncthreads();
  for(int o=128;o;o>>=1){ if(t<o) red[t]=fmaxf(red[t],red[t+o]); __syncthreads(); }
  mx = red[0]; __syncthreads();
  float sum = 0.f;
  for(int n=t;n<Nn;n+=256) sum += __expf(s[n]-mx);
  red[t] = sum; __syncthreads();
  for(int o=128;o;o>>=1){ if(t<o) red[t]+=red[t+o]; __syncthreads(); }
  if(t==0){ stat[((size_t)p*NB + b)*2] = mx; stat[((size_t)p*NB + b)*2+1] = 1.f/red[0]; }
}

__global__ __launch_bounds__(128) void k_pool_wsum(const unsigned short* __restrict__ x2,
    const float* __restrict__ sc, const float* __restrict__ stat,
    float* __restrict__ part){
  int p = blockIdx.z, b = blockIdx.x, c = blockIdx.y, t = threadIdx.x;
  int Nn = PNN[p];
  if(c*PCH >= Nn) return;
  __shared__ float wsh[PCH];
  float mx  = stat[((size_t)p*NB + b)*2];
  float inv = stat[((size_t)p*NB + b)*2+1];
  if(t < PCH) wsh[t] = __expf(sc[((size_t)p*NB + b)*2048 + c*PCH + t] - mx)*inv;
  __syncthreads();
  const unsigned short* f = x2 + POFF[p] + ((size_t)b*Nn + c*PCH)*ND;
  float acc = 0.f;
  #pragma unroll 8
  for(int n=0;n<PCH;n++) acc += wsh[n]*b2f(f[(size_t)n*ND + t]);
  part[(((size_t)p*NB + b)*MAXCH + c)*ND + t] = acc;
}

__global__ __launch_bounds__(128) void k_pool_comb(const float* __restrict__ part,
    float* __restrict__ pooled){
  int p = blockIdx.z, b = blockIdx.x, t = threadIdx.x;
  int nch = PNN[p]/PCH;
  float s = 0.f;
  for(int c=0;c<nch;c++) s += part[(((size_t)p*NB + b)*MAXCH + c)*ND + t];
  pooled[((size_t)p*NB + b)*ND + t] = s;
}

// ---- semantic attention + fuse ----
__global__ __launch_bounds__(128) void k_sem(const float* __restrict__ ctp,
    const float* __restrict__ petp, const float* __restrict__ genp,
    const float* __restrict__ Wsem, const float* __restrict__ bsem,
    const float* __restrict__ qsem, float* __restrict__ fused, float* __restrict__ beta){
  int b = blockIdx.x, t = threadIdx.x;
  __shared__ float z[3][256];
  __shared__ float red[128];
  float ct = ctp[b*ND + t], pet = petp[b*ND + t], gen = genp[b*ND + t];
  z[0][t]=ct;  z[1][t]=pet; z[2][t]=0.5f*(ct+pet);
  z[0][ND+t]=gen; z[1][ND+t]=gen; z[2][ND+t]=gen;
  __syncthreads();
  float s[3];
  for(int p=0;p<3;p++){
    float a = bsem[t];
    for(int f=0;f<256;f++) a += z[p][f]*Wsem[f*128 + t];
    a = tanhf(a);
    red[t] = a * qsem[t];
    __syncthreads();
    for(int o=64;o>0;o>>=1){ if(t<o) red[t]+=red[t+o]; __syncthreads(); }
    s[p] = red[0]; __syncthreads();
  }
  float mx = fmaxf(s[0], fmaxf(s[1], s[2]));
  float e0 = __expf(s[0]-mx), e1 = __expf(s[1]-mx), e2 = __expf(s[2]-mx);
  float sm = e0+e1+e2;
  float b0 = e0/sm, b1 = e1/sm, b2 = e2/sm;
  if(t < 3) beta[b*3 + t] = (t==0)?b0:((t==1)?b1:b2);
  float f0 = b0*z[0][t] + b1*z[1][t] + b2*z[2][t];
  float f1 = b0*z[0][ND+t] + b1*z[1][ND+t] + b2*z[2][ND+t];
  fused[(size_t)b*512 + t]       = f0;
  fused[(size_t)b*512 + 128 + t] = f1;
  fused[(size_t)b*512 + 256 + t] = 0.f;
  fused[(size_t)b*512 + 384 + t] = 0.f;
}

extern "C" void kernel_launch(void* const* d_in, const int* in_sizes, int n_in,
                              void* d_out, int out_size, void* d_ws, size_t ws_size,
                              hipStream_t stream) {
  // live relations lr0..4 = orig {r0 ct>ct, r1 pet>pet, r3 gen>gen, r5 ct>gen, r6 pet>gen}
  static const int edgein[5] = {5,6,8,10,11};
  static const int l2E[5]    = {13,13,14,13,13};
  static const int Nd_l[5]   = {1024,1024,2048,2048,2048};
  static const int E_l[5]    = {8192,8192,16384,8192,8192};
  static const int Ns_l[5]   = {1024,1024,2048,1024,1024};
  static const int eoff[6]   = {0,262144,524288,1048576,1310720,1572864};
  static const int roff[5]   = {0,32800,65600,131168,196736};
  static const unsigned long long aoff[5]   = {0,131072,262144,524288,655360};
  static const unsigned long long aldoff[5] = {0,131072,262144,524288,786432};
  static const unsigned long long hsoff_lr[5] = {0ull,4194304ull,8388608ull,16777216ull,20971520ull};
  static const unsigned long long ALD = 786432;

  const float* Wsrc = (const float*)d_in[13];
  const float* Wp   = (const float*)d_in[17];
  const float* bp   = (const float*)d_in[18];
  const float* Wsem = (const float*)d_in[19];
  const float* bsem = (const float*)d_in[20];
  const float* qsem = (const float*)d_in[21];

  unsigned short* xc16 = (unsigned short*)d_ws;               // 16,777,216 us (layer-0 in; reused as layer-1 out)
  unsigned short* x2b16 = xc16;                               // alias: final features (bf16)
  unsigned short* xmid16 = xc16 + 16777216;                   // 16,777,216 us (layer-0 out / layer-1 in)
  float* albase = (float*)(xmid16 + 16777216);                // 1,835,008 f
  float* als = albase;
  float* ald = albase + ALD;
  float* vbuf = albase + 1835008;                             // 10,240 f
  unsigned short* wfbuf = (unsigned short*)(vbuf + 10240);    // 163,840 us
  float* pooled = (float*)(wfbuf + 163840);                   // 12,288
  float* part = pooled + 12288;                               // 393,216
  float* qbuf = part + 393216;                                // 12,288
  float* scbuf = qbuf + 12288;                                // 196,608
  float* stat = scbuf + 196608;                               // 192
  int* rowstart = (int*)(stat + 192);                         // 262,304
  int* srcidx = rowstart + 262304;                            // 1,572,864
  unsigned short* hs16 = (unsigned short*)(srcidx + 1572864); // 25,165,824 us (50.3 MB)

  // ---- fold attention vectors + pre-pack W fragments ----
  { dim3 g(5,2,2); k_fold<<<g,128,0,stream>>>(Wsrc, (const float*)d_in[14],
                                              (const float*)d_in[15], (const float*)d_in[16], vbuf); }
  { dim3 g(5,2); k_wpack<<<g,256,0,stream>>>(Wsrc, wfbuf); }

  // ---- fused CSR build ----
  CsrP csr;
  for(int r=0;r<5;r++){
    csr.eg[r] = (const int*)d_in[edgein[r]];
    csr.l2E[r] = l2E[r]; csr.Nd_[r] = Nd_l[r];
    csr.roff_[r] = roff[r]; csr.eoff_[r] = eoff[r];
  }
  { dim3 g(NB,5); k_csr<<<g,512,0,stream>>>(csr, rowstart, srcidx); }

  // ---- convert inputs to bf16 ----
  k_conv<<<8192,256,0,stream>>>((const float*)d_in[0], (const float*)d_in[1],
                                (const float*)d_in[3], xc16);

  static const unsigned long long xoo[3] = {0,4194304,8388608};
  // type order in fused grid: 0=gen (long blocks first), 1=ct, 2=pet
  static const int t2_nrel[3] = {3,1,1};
  static const int t2_lrel[3][3] = {{2,3,4},{0,0,0},{1,0,0}};
  static const int t2_nds[3] = {11,10,10};
  static const int t2_out[3] = {2,0,1};

  Fu3P fp;
  fp.tboff[0]=0; fp.tboff[1]=4096; fp.tboff[2]=6144; fp.tboff[3]=8192;
  for(int t=0;t<3;t++){
    fp.nrel[t]=t2_nrel[t]; fp.ndshift[t]=t2_nds[t]; fp.outoff[t]=xoo[t2_out[t]];
    for(int q=0;q<3;q++){
      int lr = t2_lrel[t][q];
      fp.roff[t][q]=roff[lr]; fp.eoff[t][q]=eoff[lr];
      fp.E[t][q]=E_l[lr]; fp.Ns[t][q]=Ns_l[lr];
      fp.aoff[t][q]=aoff[lr]; fp.aldo[t][q]=aldoff[lr];
      fp.hoff[t][q]=hsoff_lr[lr];
    }
  }

  // k_hs grid decode: type order 0=ct, 1=pet, 2=gen; lr per (t,rep): ct{0,3}, pet{1,4}, gen{2}
  HsP hp;
  hp.tb[0]=0; hp.tb[1]=2048; hp.tb[2]=4096; hp.tb[3]=8192;
  hp.xoff[0]=0; hp.xoff[1]=4194304; hp.xoff[2]=8388608;
  hp.Ns[0]=1024; hp.Ns[1]=1024; hp.Ns[2]=2048;
  hp.nW[0]=2; hp.nW[1]=2; hp.nW[2]=1;
  hp.hso[0][0]=hsoff_lr[0]; hp.hso[0][1]=hsoff_lr[3];
  hp.hso[1][0]=hsoff_lr[1]; hp.hso[1][1]=hsoff_lr[4];
  hp.hso[2][0]=hsoff_lr[2]; hp.hso[2][1]=0;
  static const int hs_lr[3][2] = {{0,3},{1,4},{2,2}};

  for(int l=0;l<2;l++){
    const unsigned short* xcur = (l==0) ? xc16 : xmid16;
    unsigned short* xout = (l==0) ? xmid16 : x2b16;

    AlP ap;
    ap.useh = l;
    ap.xf[0]=(const float*)d_in[0]; ap.xf[1]=(const float*)d_in[1]; ap.xf[2]=(const float*)d_in[3];
    ap.xh[0]=xmid16; ap.xh[1]=xmid16+4194304; ap.xh[2]=xmid16+8388608;
    ap.boff[0]=0; ap.boff[1]=512; ap.boff[2]=1024; ap.boff[3]=2048;
    ap.nv[0]=3; ap.nv[1]=3; ap.nv[2]=4;
    int vi[3][4] = {{0,1,6,0},{2,3,8,0},{4,5,7,9}};
    unsigned long long oo[3][4] = {{0, ALD+0, 524288, 0},
                                   {131072, ALD+131072, 655360, 0},
                                   {262144, ALD+262144, ALD+524288, ALD+786432}};
    for(int t=0;t<3;t++) for(int q=0;q<4;q++){ ap.vidx[t][q]=vi[t][q]; ap.ooff[t][q]=oo[t][q]; }
    k_al<<<2048,256,0,stream>>>(ap, vbuf + (size_t)l*5120, albase);

    for(int t=0;t<3;t++)
      for(int rep=0;rep<2;rep++)
        hp.wfo[t][rep]=(unsigned long long)((l*5 + hs_lr[t][rep])*4)*4096;
    k_hs<<<8192,256,0,stream>>>(hp, xcur, wfbuf, hs16);

    k_fuse3<<<8192,256,0,stream>>>(fp, rowstart, srcidx, als, ald, hs16, xout);
  }

  // ---- pooling (bf16 features) ----
  {
    dim3 gchunk(NB, MAXCH, 3);
    dim3 gone(NB, 1, 3);
    dim3 gscore(512, NB, 3);
    k_pool_psum <<<gchunk,128,0,stream>>>(x2b16, part);
    k_pool_q    <<<gone,  128,0,stream>>>(part, Wp, bp, qbuf);
    k_pool_score<<<gscore,256,0,stream>>>(x2b16, qbuf, scbuf);
    k_pool_smax <<<gone,  256,0,stream>>>(scbuf, stat);
    k_pool_wsum <<<gchunk,128,0,stream>>>(x2b16, scbuf, stat, part);
    k_pool_comb <<<gone,  128,0,stream>>>(part, pooled);
  }

  float* fused = (float*)d_out;
  float* beta  = fused + (size_t)NB*512;
  k_sem<<<NB,128,0,stream>>>(pooled, pooled + NB*ND, pooled + 2*NB*ND,
                             Wsem, bsem, qsem, fused, beta);
}

// Round 2
// 366.658 us; speedup vs baseline: 1.2881x; 1.1531x over previous
//
#include <hip/hip_runtime.h>
#include <math.h>

static constexpr int NB = 32;
static constexpr int ND = 128;

typedef short bf16x8 __attribute__((ext_vector_type(8)));
typedef float f32x4  __attribute__((ext_vector_type(4)));
typedef unsigned short u16x8 __attribute__((ext_vector_type(8)));

__device__ __forceinline__ float lrelu(float x){ return x > 0.f ? x : 0.2f*x; }
__device__ __forceinline__ unsigned short f2b(float f){
  unsigned u = __float_as_uint(f);
  return (unsigned short)((u + 0x7FFFu + ((u>>16)&1u)) >> 16);
}
__device__ __forceinline__ float b2f(unsigned short b){
  return __uint_as_float(((unsigned)b) << 16);
}

// ---- fold v[k][h] = sum_j W[k][h*32+j]*a[h*32+j] for all (layer, liverel, role) ----
__global__ __launch_bounds__(128) void k_fold(const float* __restrict__ Wsrc,
    const float* __restrict__ Wdst, const float* __restrict__ asrc,
    const float* __restrict__ adst, float* __restrict__ vbuf){
  const int wid[5] = {0,1,3,5,6};
  int lr = blockIdx.x, role = blockIdx.y, l = blockIdx.z;
  int r = wid[lr];
  const float* W = (role ? Wdst : Wsrc) + (size_t)(l*8+r)*16384;
  const float* a = (role ? adst : asrc) + (size_t)(l*8+r)*128;
  int k = threadIdx.x;
  float* o = vbuf + ((size_t)((l*5+lr)*2+role))*512 + k*4;
  #pragma unroll
  for(int h=0;h<4;h++){
    float s = 0.f;
    #pragma unroll
    for(int j=0;j<32;j++) s += W[k*128 + h*32 + j]*a[h*32 + j];
    o[h] = s;
  }
}

// ---- pre-pack W_src (5 live rels x 2 layers) into bf16 MFMA B-fragment layout ----
__global__ __launch_bounds__(256) void k_wpack(const float* __restrict__ Wsrc,
    unsigned short* __restrict__ Wf){
  const int wid[5] = {0,1,3,5,6};
  int lr = blockIdx.x, l = blockIdx.y;
  const float* W = Wsrc + (size_t)(l*8+wid[lr])*16384;
  unsigned short* o = Wf + (size_t)((l*5+lr)*4)*4096;
  for(int idx=threadIdx.x; idx<128*128; idx+=256){
    int k = idx >> 7, col = idx & 127;
    int h = col >> 5, cc = col & 31;
    int k4 = k>>2, g = k4&3, kk = k4>>3, j = 4*((k4>>2)&1) + (k&3);
    int nb = cc>>4, lane = (cc&15) + 16*g;
    o[(size_t)h*4096 + ((size_t)((kk*2+nb)*64 + lane))*8 + j] = f2b(W[k*128 + col]);
  }
}

// ---- convert fp32 inputs (ct,pet,gen) -> bf16 ----
__global__ __launch_bounds__(256) void k_conv(const float* __restrict__ i0,
    const float* __restrict__ i1, const float* __restrict__ i2,
    unsigned short* __restrict__ x16){
  int bx = blockIdx.x;
  const float* src; size_t base; unsigned short* dst;
  if(bx < 2048){ src=i0; base=(size_t)bx*2048; dst=x16; }
  else if(bx < 4096){ src=i1; base=(size_t)(bx-2048)*2048; dst=x16+4194304; }
  else { src=i2; base=(size_t)(bx-4096)*2048; dst=x16+8388608; }
  size_t o = base + (size_t)threadIdx.x*8;
  float4 a = *(const float4*)(src+o), b = *(const float4*)(src+o+4);
  u16x8 r;
  r[0]=f2b(a.x); r[1]=f2b(a.y); r[2]=f2b(a.z); r[3]=f2b(a.w);
  r[4]=f2b(b.x); r[5]=f2b(b.y); r[6]=f2b(b.z); r[7]=f2b(b.w);
  *(u16x8*)(dst+o) = r;
}

// ================= fused CSR build: count+scan+fill in ONE kernel via LDS =================
struct CsrP {
  const int* eg[5];
  int l2E[5];
  int Nd_[5];
  int roff_[5];
  int eoff_[5];
};

__global__ __launch_bounds__(512) void k_csr(CsrP P, int* __restrict__ rowstart,
                                             int* __restrict__ srcidx){
  int b = blockIdx.x, r = blockIdx.y, t = threadIdx.x;
  int E = 1<<P.l2E[r], Nd = P.Nd_[r];
  const int* eg = P.eg[r] + (size_t)b*2*E;
  int* rsO = rowstart + P.roff_[r] + b*(Nd+1);
  int* siO = srcidx + P.eoff_[r] + (size_t)b*E;
  __shared__ int cnt[2048];
  __shared__ int stmp[512];
  for(int i=t;i<Nd;i+=512) cnt[i]=0;
  __syncthreads();
  for(int e=t;e<E;e+=512) atomicAdd(&cnt[eg[E+e]], 1);
  __syncthreads();
  int carry=0;
  for(int c0=0;c0<Nd;c0+=512){
    int idx=c0+t;
    int v=(idx<Nd)?cnt[idx]:0;
    stmp[t]=v; __syncthreads();
    for(int off=1;off<512;off<<=1){
      int u=(t>=off)?stmp[t-off]:0;
      __syncthreads();
      stmp[t]+=u;
      __syncthreads();
    }
    int excl=stmp[t]-v+carry;
    if(idx<Nd){ rsO[idx]=excl; cnt[idx]=excl; }
    int tot = stmp[511];
    __syncthreads();
    carry+=tot;
  }
  if(t==0) rsO[Nd]=carry;
  __syncthreads();
  for(int e=t;e<E;e+=512){
    int src=eg[e], dst=eg[E+e];
    int pos=atomicAdd(&cnt[dst],1);
    siO[pos]=src;
  }
}

// ================= dense hs = x @ W_src per relation (bf16 MFMA) + al_s/al_d epilogues ======
// Block: 256 thr = 4 waves, 16 rows of one (b, type). ct/pet tiles compute 2 W's (self + ->gen).
// al_s[n,h] = sum_c hs_f32[n, h*32+c] * a_src[h,c]  (free from MFMA accumulators)
// al_d[n,h] = sum_k x[n,k] * v_dst[k,h]             (folded vector, x already in LDS)
struct HsP {
  int tb[4];
  unsigned long long xoff[3];
  int Ns[3];
  int nW[3];
  unsigned long long wfo[3][2];
  unsigned long long hso[3][2];
  unsigned long long aso[3][2];    // als float offsets per rep
  unsigned long long asrco[3][2];  // a_src float offsets per rep (layer-dep)
  int nvd[3];
  unsigned long long vdo[3][3];    // vbuf float offsets (dst vecs, layer-dep)
  unsigned long long aldo2[3][3];  // ald float offsets
  int ndd[3][3];                   // Nd per dst-rel
};

__global__ __launch_bounds__(256) void k_hs(HsP P, const unsigned short* __restrict__ x16,
    const unsigned short* __restrict__ Wf, const float* __restrict__ asrc,
    const float* __restrict__ vbuf, unsigned short* __restrict__ hs,
    float* __restrict__ als, float* __restrict__ ald){
  __shared__ unsigned short xl[16*132];
  int B = blockIdx.x;
  int t=0; while(t<2 && B>=P.tb[t+1]) t++;
  int local = B - P.tb[t];
  int b = local & 31, tile = local >> 5;
  int n0 = tile*16;
  int tid = threadIdx.x, w = tid>>6, ln = tid&63;
  {
    int row = tid>>4, ch = tid&15;
    u16x8 v = *(const u16x8*)(x16 + P.xoff[t] + ((size_t)((size_t)b*P.Ns[t] + n0+row)*128 + ch*8));
    *(u16x8*)&xl[row*132 + ch*8] = v;
  }
  __syncthreads();
  int g = ln>>4, r15 = ln&15;
  for(int rep=0; rep<P.nW[t]; rep++){
    const unsigned short* wf = Wf + P.wfo[t][rep] + (size_t)w*4096;
    f32x4 acc[2]; acc[0]=(f32x4){0,0,0,0}; acc[1]=(f32x4){0,0,0,0};
    #pragma unroll
    for(int kk=0;kk<4;kk++){
      const unsigned short* pa = &xl[r15*132 + kk*32 + 4*g];
      ushort4 lo = *(const ushort4*)pa;
      ushort4 hi = *(const ushort4*)(pa+16);
      union { ushort u[8]; bf16x8 v; } tmp;
      tmp.u[0]=lo.x; tmp.u[1]=lo.y; tmp.u[2]=lo.z; tmp.u[3]=lo.w;
      tmp.u[4]=hi.x; tmp.u[5]=hi.y; tmp.u[6]=hi.z; tmp.u[7]=hi.w;
      bf16x8 af = tmp.v;
      #pragma unroll
      for(int nb=0;nb<2;nb++){
        bf16x8 bw = *(const bf16x8*)(wf + ((size_t)((kk*2+nb)*64 + ln))*8);
        acc[nb] = __builtin_amdgcn_mfma_f32_16x16x32_bf16(af, bw, acc[nb], 0, 0, 0);
      }
    }
    unsigned short* ho = hs + P.hso[t][rep] + ((size_t)b*P.Ns[t] + n0)*128;
    #pragma unroll
    for(int qq=0;qq<4;qq++){
      int m = 4*g + qq;
      #pragma unroll
      for(int nb=0;nb<2;nb++){
        ho[(size_t)m*128 + w*32 + nb*16 + r15] = f2b(acc[nb][qq]);
      }
    }
    // ---- al_s epilogue: reduce acc over cols of head w ----
    {
      const float* aS = asrc + P.asrco[t][rep];
      float a0v = aS[w*32 + r15], a1v = aS[w*32 + 16 + r15];
      float p0 = acc[0][0]*a0v + acc[1][0]*a1v;
      float p1 = acc[0][1]*a0v + acc[1][1]*a1v;
      float p2 = acc[0][2]*a0v + acc[1][2]*a1v;
      float p3 = acc[0][3]*a0v + acc[1][3]*a1v;
      #pragma unroll
      for(int off=1; off<16; off<<=1){
        p0 += __shfl_xor(p0,off); p1 += __shfl_xor(p1,off);
        p2 += __shfl_xor(p2,off); p3 += __shfl_xor(p3,off);
      }
      if(r15 < 4){
        float pv = (r15==0)?p0:((r15==1)?p1:((r15==2)?p2:p3));
        als[P.aso[t][rep] + ((size_t)b*P.Ns[t] + n0 + 4*g + r15)*4 + w] = pv;
      }
    }
  }
  // ---- al_d: x-tile (LDS) dot folded dst vectors ----
  int nvd = P.nvd[t];
  if(tid < (nvd<<6)){
    int vd = tid>>6, rem = tid&63, row = rem>>2, h = rem&3;
    const float* vv = vbuf + P.vdo[t][vd];
    float s = 0.f;
    #pragma unroll 8
    for(int k=0;k<128;k++) s += b2f(xl[row*132+k]) * vv[k*4+h];
    ald[P.aldo2[t][vd] + ((size_t)b*P.ndd[t][vd] + n0 + row)*4 + h] = s;
  }
}

// ========= fused softmax + gather, 64-dst tiles, all relations merged, 3 barriers =========
static constexpr int MAXE4 = 1536;  // concat edge cap: gen mean 1024, sigma ~32 -> +16 sigma
static constexpr int WST4  = 1544;  // head-major wlds stride (1544%32=8 -> staggered banks)

struct Fu4P {
  int tboff[4];
  int nrel[3], ndshift[3];
  int roff[3][3], eoff[3][3], E[3][3], Ns[3][3];
  unsigned long long aoff[3][3], aldo[3][3];
  unsigned long long hoff[3][3];
  unsigned long long outoff[3];
};

__global__ __launch_bounds__(512, 8) void k_fuse4(Fu4P P,
    const int* __restrict__ rowstart, const int* __restrict__ srcidx,
    const float* __restrict__ als, const float* __restrict__ ald,
    const unsigned short* __restrict__ hs, unsigned short* __restrict__ out16){
  __shared__ float wlds[4*WST4];   // 24.7 KB
  __shared__ int   silds[MAXE4];   // 6 KB
  __shared__ float aldl[3*256];    // 3 KB
  __shared__ int   rsl[3*65];      // 780 B
  __shared__ int   ebo[3], baseo[3];
  int B = blockIdx.x;
  int t=0; while(t<2 && B>=P.tboff[t+1]) t++;
  int local = B - P.tboff[t];
  int b = local & 31, dtile = local >> 5;
  int Nd = 1 << P.ndshift[t];
  int d0 = dtile * 64;
  int tid = threadIdx.x, w = tid>>6, ln = tid&63;
  int nrel = P.nrel[t];

  // ---- phase0: stage rsl rows, aldl, silds; compute concat offsets ----
  {
    int acc_base = 0;
    #pragma unroll
    for(int q=0;q<3;q++){
      if(q < nrel){
        const int* rsq = rowstart + P.roff[t][q] + b*(Nd+1) + d0;
        int eb = rsq[0];
        int cnt = rsq[64] - eb;
        if(tid==0){ ebo[q]=eb; baseo[q]=acc_base; }
        for(int i=tid; i<65; i+=512) rsl[q*65+i] = rsq[i];
        const float* aldq = ald + P.aldo[t][q] + ((size_t)b*Nd + d0)*4;
        for(int i=tid; i<256; i+=512) aldl[(q<<8)+i] = aldq[i];
        const int* si = srcidx + P.eoff[t][q] + (size_t)b*P.E[t][q] + eb;
        for(int e=tid; e<cnt; e+=512) silds[acc_base + e] = si[e];
        acc_base += cnt;
      }
    }
  }
  __syncthreads();

  // ---- pass1: logits, one thread per (rel,dst,j): 1 float4 als gather, ald from LDS ----
  for(int s=tid; s<(nrel<<8); s+=512){
    int q = s>>8, rem = s&255, dloc = rem>>2, j = rem&3;
    int eb = ebo[q], bo = baseo[q];
    int e0 = bo + rsl[q*65+dloc] - eb;
    int e1 = bo + rsl[q*65+dloc+1] - eb;
    const float* alsb = als + P.aoff[t][q] + (size_t)b*P.Ns[t][q]*4;
    float4 ad4 = *(const float4*)&aldl[(q<<8) + (dloc<<2)];
    for(int e=e0+j; e<e1; e+=4){
      int sidx = silds[e];
      float4 as4 = *(const float4*)(alsb + (size_t)sidx*4);
      wlds[0*WST4+e] = lrelu(as4.x+ad4.x);
      wlds[1*WST4+e] = lrelu(as4.y+ad4.y);
      wlds[2*WST4+e] = lrelu(as4.z+ad4.z);
      wlds[3*WST4+e] = lrelu(as4.w+ad4.w);
    }
  }
  __syncthreads();

  // ---- pass2: segmented softmax, one thread per (rel,dst,head), LDS only ----
  for(int s=tid; s<(nrel<<8); s+=512){
    int q = s>>8, rem = s&255, dloc = rem>>2, h2 = rem&3;
    int eb = ebo[q], bo = baseo[q];
    int e0 = bo + rsl[q*65+dloc] - eb;
    int e1 = bo + rsl[q*65+dloc+1] - eb;
    float* wrow = &wlds[h2*WST4];
    float m = -1e30f;
    for(int e=e0;e<e1;e++) m = fmaxf(m, wrow[e]);
    float den = 0.f;
    for(int e=e0;e<e1;e++){ float p=__expf(wrow[e]-m); wrow[e]=p; den+=p; }
    float inv = 1.f/(den + 1e-16f);
    for(int e=e0;e<e1;e++) wrow[e] *= inv;
  }
  __syncthreads();

  // ---- pass3: weighted gather of hs rows, 8 dsts per wave ----
  int h = ln>>4;
  float accA[8], accB[8];
  #pragma unroll
  for(int i=0;i<8;i++){ accA[i]=0.f; accB[i]=0.f; }
  for(int q=0;q<nrel;q++){
    const unsigned short* hb = hs + P.hoff[t][q] + (size_t)b*P.Ns[t][q]*128;
    int eb = ebo[q], bo = baseo[q];
    #pragma unroll
    for(int it=0; it<8; it++){
      int dloc = w*8 + it;
      int e0 = bo + rsl[q*65+dloc] - eb;
      int e1 = bo + rsl[q*65+dloc+1] - eb;
      float a0 = 0.f, a1 = 0.f;
      int e = e0;
      int eal = (e0+3)&~3; if(eal > e1) eal = e1;
      for(; e<eal; e++){
        float wv = wlds[h*WST4 + e];
        unsigned v = *(const unsigned*)(hb + ((size_t)silds[e]*128 + 2*ln));
        a0 += wv*__uint_as_float(v<<16);
        a1 += wv*__uint_as_float(v&0xFFFF0000u);
      }
      for(; e+4<=e1; e+=4){
        int4  sq = *(const int4*)&silds[e];
        float4 wq = *(const float4*)&wlds[h*WST4 + e];
        unsigned v0 = *(const unsigned*)(hb + ((size_t)sq.x*128 + 2*ln));
        unsigned v1 = *(const unsigned*)(hb + ((size_t)sq.y*128 + 2*ln));
        unsigned v2 = *(const unsigned*)(hb + ((size_t)sq.z*128 + 2*ln));
        unsigned v3 = *(const unsigned*)(hb + ((size_t)sq.w*128 + 2*ln));
        a0 += wq.x*__uint_as_float(v0<<16); a1 += wq.x*__uint_as_float(v0&0xFFFF0000u);
        a0 += wq.y*__uint_as_float(v1<<16); a1 += wq.y*__uint_as_float(v1&0xFFFF0000u);
        a0 += wq.z*__uint_as_float(v2<<16); a1 += wq.z*__uint_as_float(v2&0xFFFF0000u);
        a0 += wq.w*__uint_as_float(v3<<16); a1 += wq.w*__uint_as_float(v3&0xFFFF0000u);
      }
      for(; e<e1; e++){
        float wv = wlds[h*WST4 + e];
        unsigned v = *(const unsigned*)(hb + ((size_t)silds[e]*128 + 2*ln));
        a0 += wv*__uint_as_float(v<<16);
        a1 += wv*__uint_as_float(v&0xFFFF0000u);
      }
      accA[it] += a0; accB[it] += a1;
    }
  }
  // ---- epilogue: ELU + bf16 store ----
  #pragma unroll
  for(int it=0; it<8; it++){
    int m = d0 + w*8 + it;
    float v0 = accA[it], v1 = accB[it];
    v0 = v0 > 0.f ? v0 : expm1f(v0);
    v1 = v1 > 0.f ? v1 : expm1f(v1);
    ushort2 o; o.x = f2b(v0); o.y = f2b(v1);
    *(ushort2*)(out16 + P.outoff[t] + ((size_t)b*Nd + m)*128 + 2*ln) = o;
  }
}

// ================= pooling (3 pools batched via blockIdx.z; bf16 features) =================
__device__ __constant__ const size_t POFF[3] = {0ull, 4194304ull, 8388608ull};
__device__ __constant__ const int    PNN[3]  = {1024, 1024, 2048};
static constexpr int PCH = 64;
static constexpr int MAXCH = 32;

__global__ __launch_bounds__(128) void k_pool_psum(const unsigned short* __restrict__ x2,
    float* __restrict__ part){
  int p = blockIdx.z, b = blockIdx.x, c = blockIdx.y, t = threadIdx.x;
  int Nn = PNN[p];
  if(c*PCH >= Nn) return;
  const unsigned short* f = x2 + POFF[p] + ((size_t)b*Nn + c*PCH)*ND;
  float acc = 0.f;
  #pragma unroll 8
  for(int n=0;n<PCH;n++) acc += b2f(f[(size_t)n*ND + t]);
  part[(((size_t)p*NB + b)*MAXCH + c)*ND + t] = acc;
}

__global__ __launch_bounds__(128) void k_pool_q(const float* __restrict__ part,
    const float* __restrict__ Wp, const float* __restrict__ bp,
    float* __restrict__ q){
  int p = blockIdx.z, b = blockIdx.x, t = threadIdx.x;
  int nch = PNN[p]/PCH;
  __shared__ float mean[ND];
  float s = 0.f;
  for(int c=0;c<nch;c++) s += part[(((size_t)p*NB + b)*MAXCH + c)*ND + t];
  mean[t] = s / (float)PNN[p];
  __syncthreads();
  const float* W = Wp + (size_t)p*ND*ND;
  float qv = bp[p*ND + t];
  #pragma unroll 8
  for(int k=0;k<ND;k++) qv += mean[k]*W[k*ND + t];
  q[((size_t)p*NB + b)*ND + t] = qv;
}

__global__ __launch_bounds__(256) void k_pool_score(const unsigned short* __restrict__ x2,
    const float* __restrict__ q, float* __restrict__ sc){
  int p = blockIdx.z, b = blockIdx.y;
  int w = threadIdx.x >> 6, lane = threadIdx.x & 63;
  int n = blockIdx.x*4 + w;
  int Nn = PNN[p];
  if(n >= Nn) return;
  const unsigned short* f  = x2 + POFF[p] + ((size_t)b*Nn + n)*ND;
  const float* qb = q + ((size_t)p*NB + b)*ND;
  float s = b2f(f[lane])*qb[lane] + b2f(f[lane+64])*qb[lane+64];
  #pragma unroll
  for(int off=32; off; off>>=1) s += __shfl_xor(s, off);
  if(lane == 0) sc[((size_t)p*NB + b)*2048 + n] = s;
}

__global__ __launch_bounds__(256) void k_pool_smax(const float* __restrict__ sc,
    float* __restrict__ stat){
  int p = blockIdx.z, b = blockIdx.x, t = threadIdx.x;
  int Nn = PNN[p];
  __shared__ float red[256];
  const float* s = sc + ((size_t)p*NB + b)*2048;
  float mx = -1e30f;
  for(int n=t;n<Nn;n+=256) mx = fmaxf(mx, s[n]);
  red[t] = mx; __syncthreads();
  for(int o=128;o;o>>=1){ if(t<o) red[t]=fmaxf(red[t],red[t+o]); __syncthreads(); }
  mx = red[0]; __syncthreads();
  float sum = 0.f;
  for(int n=t;n<Nn;n+=256) sum += __expf(s[n]-mx);
  red[t] = sum; __syncthreads();
  for(int o=128;o;o>>=1){ if(t<o) red[t]+=red[t+o]; __syncthreads(); }
  if(t==0){ stat[((size_t)p*NB + b)*2] = mx; stat[((size_t)p*NB + b)*2+1] = 1.f/red[0]; }
}

__global__ __launch_bounds__(128) void k_pool_wsum(const unsigned short* __restrict__ x2,
    const float* __restrict__ sc, const float* __restrict__ stat,
    float* __restrict__ part){
  int p = blockIdx.z, b = blockIdx.x, c = blockIdx.y, t = threadIdx.x;
  int Nn = PNN[p];
  if(c*PCH >= Nn) return;
  __shared__ float wsh[PCH];
  float mx  = stat[((size_t)p*NB + b)*2];
  float inv = stat[((size_t)p*NB + b)*2+1];
  if(t < PCH) wsh[t] = __expf(sc[((size_t)p*NB + b)*2048 + c*PCH + t] - mx)*inv;
  __syncthreads();
  const unsigned short* f = x2 + POFF[p] + ((size_t)b*Nn + c*PCH)*ND;
  float acc = 0.f;
  #pragma unroll 8
  for(int n=0;n<PCH;n++) acc += wsh[n]*b2f(f[(size_t)n*ND + t]);
  part[(((size_t)p*NB + b)*MAXCH + c)*ND + t] = acc;
}

__global__ __launch_bounds__(128) void k_pool_comb(const float* __restrict__ part,
    float* __restrict__ pooled){
  int p = blockIdx.z, b = blockIdx.x, t = threadIdx.x;
  int nch = PNN[p]/PCH;
  float s = 0.f;
  for(int c=0;c<nch;c++) s += part[(((size_t)p*NB + b)*MAXCH + c)*ND + t];
  pooled[((size_t)p*NB + b)*ND + t] = s;
}

// ---- semantic attention + fuse ----
__global__ __launch_bounds__(128) void k_sem(const float* __restrict__ ctp,
    const float* __restrict__ petp, const float* __restrict__ genp,
    const float* __restrict__ Wsem, const float* __restrict__ bsem,
    const float* __restrict__ qsem, float* __restrict__ fused, float* __restrict__ beta){
  int b = blockIdx.x, t = threadIdx.x;
  __shared__ float z[3][256];
  __shared__ float red[128];
  float ct = ctp[b*ND + t], pet = petp[b*ND + t], gen = genp[b*ND + t];
  z[0][t]=ct;  z[1][t]=pet; z[2][t]=0.5f*(ct+pet);
  z[0][ND+t]=gen; z[1][ND+t]=gen; z[2][ND+t]=gen;
  __syncthreads();
  float s[3];
  for(int p=0;p<3;p++){
    float a = bsem[t];
    for(int f=0;f<256;f++) a += z[p][f]*Wsem[f*128 + t];
    a = tanhf(a);
    red[t] = a * qsem[t];
    __syncthreads();
    for(int o=64;o>0;o>>=1){ if(t<o) red[t]+=red[t+o]; __syncthreads(); }
    s[p] = red[0]; __syncthreads();
  }
  float mx = fmaxf(s[0], fmaxf(s[1], s[2]));
  float e0 = __expf(s[0]-mx), e1 = __expf(s[1]-mx), e2 = __expf(s[2]-mx);
  float sm = e0+e1+e2;
  float b0 = e0/sm, b1 = e1/sm, b2 = e2/sm;
  if(t < 3) beta[b*3 + t] = (t==0)?b0:((t==1)?b1:b2);
  float f0 = b0*z[0][t] + b1*z[1][t] + b2*z[2][t];
  float f1 = b0*z[0][ND+t] + b1*z[1][ND+t] + b2*z[2][ND+t];
  fused[(size_t)b*512 + t]       = f0;
  fused[(size_t)b*512 + 128 + t] = f1;
  fused[(size_t)b*512 + 256 + t] = 0.f;
  fused[(size_t)b*512 + 384 + t] = 0.f;
}

extern "C" void kernel_launch(void* const* d_in, const int* in_sizes, int n_in,
                              void* d_out, int out_size, void* d_ws, size_t ws_size,
                              hipStream_t stream) {
  // live relations lr0..4 = orig {r0 ct>ct, r1 pet>pet, r3 gen>gen, r5 ct>gen, r6 pet>gen}
  static const int wid[5]    = {0,1,3,5,6};
  static const int edgein[5] = {5,6,8,10,11};
  static const int l2E[5]    = {13,13,14,13,13};
  static const int Nd_l[5]   = {1024,1024,2048,2048,2048};
  static const int E_l[5]    = {8192,8192,16384,8192,8192};
  static const int Ns_l[5]   = {1024,1024,2048,1024,1024};
  static const int eoff[6]   = {0,262144,524288,1048576,1310720,1572864};
  static const int roff[5]   = {0,32800,65600,131168,196736};
  static const unsigned long long aoff[5]   = {0,131072,262144,524288,655360};
  static const unsigned long long aldoff[5] = {0,131072,262144,524288,786432};
  static const unsigned long long hsoff_lr[5] = {0ull,4194304ull,8388608ull,16777216ull,20971520ull};
  static const unsigned long long ALD = 786432;

  const float* Wsrc = (const float*)d_in[13];
  const float* Wp   = (const float*)d_in[17];
  const float* bp   = (const float*)d_in[18];
  const float* Wsem = (const float*)d_in[19];
  const float* bsem = (const float*)d_in[20];
  const float* qsem = (const float*)d_in[21];

  unsigned short* xc16 = (unsigned short*)d_ws;               // 16,777,216 us (layer-0 in; reused as layer-1 out)
  unsigned short* x2b16 = xc16;                               // alias: final features (bf16)
  unsigned short* xmid16 = xc16 + 16777216;                   // 16,777,216 us (layer-0 out / layer-1 in)
  float* albase = (float*)(xmid16 + 16777216);                // 1,835,008 f
  float* als = albase;
  float* ald = albase + ALD;
  float* vbuf = albase + 1835008;                             // 10,240 f
  unsigned short* wfbuf = (unsigned short*)(vbuf + 10240);    // 163,840 us
  float* pooled = (float*)(wfbuf + 163840);                   // 12,288
  float* part = pooled + 12288;                               // 393,216
  float* qbuf = part + 393216;                                // 12,288
  float* scbuf = qbuf + 12288;                                // 196,608
  float* stat = scbuf + 196608;                               // 192
  int* rowstart = (int*)(stat + 192);                         // 262,304
  int* srcidx = rowstart + 262304;                            // 1,572,864
  unsigned short* hs16 = (unsigned short*)(srcidx + 1572864); // 25,165,824 us (50.3 MB)

  // ---- fold attention vectors + pre-pack W fragments ----
  { dim3 g(5,2,2); k_fold<<<g,128,0,stream>>>(Wsrc, (const float*)d_in[14],
                                              (const float*)d_in[15], (const float*)d_in[16], vbuf); }
  { dim3 g(5,2); k_wpack<<<g,256,0,stream>>>(Wsrc, wfbuf); }

  // ---- fused CSR build ----
  CsrP csr;
  for(int r=0;r<5;r++){
    csr.eg[r] = (const int*)d_in[edgein[r]];
    csr.l2E[r] = l2E[r]; csr.Nd_[r] = Nd_l[r];
    csr.roff_[r] = roff[r]; csr.eoff_[r] = eoff[r];
  }
  { dim3 g(NB,5); k_csr<<<g,512,0,stream>>>(csr, rowstart, srcidx); }

  // ---- convert inputs to bf16 ----
  k_conv<<<8192,256,0,stream>>>((const float*)d_in[0], (const float*)d_in[1],
                                (const float*)d_in[3], xc16);

  static const unsigned long long xoo[3] = {0,4194304,8388608};
  // type order in fused grid: 0=gen (3-rel blocks first), 1=ct, 2=pet
  static const int t2_nrel[3] = {3,1,1};
  static const int t2_lrel[3][3] = {{2,3,4},{0,0,0},{1,0,0}};
  static const int t2_nds[3] = {11,10,10};
  static const int t2_out[3] = {2,0,1};

  Fu4P fp;
  fp.tboff[0]=0; fp.tboff[1]=1024; fp.tboff[2]=1536; fp.tboff[3]=2048;
  for(int t=0;t<3;t++){
    fp.nrel[t]=t2_nrel[t]; fp.ndshift[t]=t2_nds[t]; fp.outoff[t]=xoo[t2_out[t]];
    for(int q=0;q<3;q++){
      int lr = t2_lrel[t][q];
      fp.roff[t][q]=roff[lr]; fp.eoff[t][q]=eoff[lr];
      fp.E[t][q]=E_l[lr]; fp.Ns[t][q]=Ns_l[lr];
      fp.aoff[t][q]=aoff[lr]; fp.aldo[t][q]=aldoff[lr];
      fp.hoff[t][q]=hsoff_lr[lr];
    }
  }

  // k_hs grid decode: type order 0=ct, 1=pet, 2=gen; reps per (t): ct{lr0,lr3}, pet{lr1,lr4}, gen{lr2}
  static const int hs_lr[3][2] = {{0,3},{1,4},{2,2}};
  static const int vd_lr[3][3] = {{0,0,0},{1,0,0},{2,3,4}};
  HsP hp;
  hp.tb[0]=0; hp.tb[1]=2048; hp.tb[2]=4096; hp.tb[3]=8192;
  hp.xoff[0]=0; hp.xoff[1]=4194304; hp.xoff[2]=8388608;
  hp.Ns[0]=1024; hp.Ns[1]=1024; hp.Ns[2]=2048;
  hp.nW[0]=2; hp.nW[1]=2; hp.nW[2]=1;
  hp.nvd[0]=1; hp.nvd[1]=1; hp.nvd[2]=3;
  for(int t=0;t<3;t++){
    for(int rep=0;rep<2;rep++){
      int lr = hs_lr[t][rep];
      hp.hso[t][rep]=hsoff_lr[lr];
      hp.aso[t][rep]=aoff[lr];
    }
    for(int vd=0;vd<3;vd++){
      int lr = vd_lr[t][vd];
      hp.aldo2[t][vd]=aldoff[lr];
      hp.ndd[t][vd]=Nd_l[lr];
    }
  }
  hp.hso[2][1]=0; hp.aso[2][1]=0;

  for(int l=0;l<2;l++){
    const unsigned short* xcur = (l==0) ? xc16 : xmid16;
    unsigned short* xout = (l==0) ? xmid16 : x2b16;

    for(int t=0;t<3;t++){
      for(int rep=0;rep<2;rep++){
        int lr = hs_lr[t][rep];
        hp.wfo[t][rep]=(unsigned long long)((l*5 + lr)*4)*4096;
        hp.asrco[t][rep]=(unsigned long long)((l*8 + wid[lr])*128);
      }
      for(int vd=0;vd<3;vd++){
        int lr = vd_lr[t][vd];
        hp.vdo[t][vd]=((unsigned long long)((l*5+lr)*2+1))*512;
      }
    }
    k_hs<<<8192,256,0,stream>>>(hp, xcur, wfbuf, (const float*)d_in[15], vbuf,
                                hs16, als, ald);

    k_fuse4<<<2048,512,0,stream>>>(fp, rowstart, srcidx, als, ald, hs16, xout);
  }

  // ---- pooling (bf16 features) ----
  {
    dim3 gchunk(NB, MAXCH, 3);
    dim3 gone(NB, 1, 3);
    dim3 gscore(512, NB, 3);
    k_pool_psum <<<gchunk,128,0,stream>>>(x2b16, part);
    k_pool_q    <<<gone,  128,0,stream>>>(part, Wp, bp, qbuf);
    k_pool_score<<<gscore,256,0,stream>>>(x2b16, qbuf, scbuf);
    k_pool_smax <<<gone,  256,0,stream>>>(scbuf, stat);
    k_pool_wsum <<<gchunk,128,0,stream>>>(x2b16, scbuf, stat, part);
    k_pool_comb <<<gone,  128,0,stream>>>(part, pooled);
  }

  float* fused = (float*)d_out;
  float* beta  = fused + (size_t)NB*512;
  k_sem<<<NB,128,0,stream>>>(pooled, pooled + NB*ND, pooled + 2*NB*ND,
                             Wsem, bsem, qsem, fused, beta);
}

// Round 3
// 335.994 us; speedup vs baseline: 1.4056x; 1.0913x over previous
//
#include <hip/hip_runtime.h>
#include <math.h>

static constexpr int NB = 32;
static constexpr int ND = 128;

typedef short bf16x8 __attribute__((ext_vector_type(8)));
typedef float f32x4  __attribute__((ext_vector_type(4)));
typedef unsigned short u16x8 __attribute__((ext_vector_type(8)));

__device__ __forceinline__ float lrelu(float x){ return x > 0.f ? x : 0.2f*x; }
__device__ __forceinline__ unsigned short f2b(float f){
  unsigned u = __float_as_uint(f);
  return (unsigned short)((u + 0x7FFFu + ((u>>16)&1u)) >> 16);
}
__device__ __forceinline__ float b2f(unsigned short b){
  return __uint_as_float(((unsigned)b) << 16);
}

// ---- fold v[k][h] = sum_j W[k][h*32+j]*a[h*32+j] for all (layer, liverel, role) ----
__global__ __launch_bounds__(128) void k_fold(const float* __restrict__ Wsrc,
    const float* __restrict__ Wdst, const float* __restrict__ asrc,
    const float* __restrict__ adst, float* __restrict__ vbuf){
  const int wid[5] = {0,1,3,5,6};
  int lr = blockIdx.x, role = blockIdx.y, l = blockIdx.z;
  int r = wid[lr];
  const float* W = (role ? Wdst : Wsrc) + (size_t)(l*8+r)*16384;
  const float* a = (role ? adst : asrc) + (size_t)(l*8+r)*128;
  int k = threadIdx.x;
  float* o = vbuf + ((size_t)((l*5+lr)*2+role))*512 + k*4;
  #pragma unroll
  for(int h=0;h<4;h++){
    float s = 0.f;
    #pragma unroll
    for(int j=0;j<32;j++) s += W[k*128 + h*32 + j]*a[h*32 + j];
    o[h] = s;
  }
}

// ---- pre-pack W_src (5 live rels x 2 layers) into bf16 MFMA B-fragment layout ----
__global__ __launch_bounds__(256) void k_wpack(const float* __restrict__ Wsrc,
    unsigned short* __restrict__ Wf){
  const int wid[5] = {0,1,3,5,6};
  int lr = blockIdx.x, l = blockIdx.y;
  const float* W = Wsrc + (size_t)(l*8+wid[lr])*16384;
  unsigned short* o = Wf + (size_t)((l*5+lr)*4)*4096;
  for(int idx=threadIdx.x; idx<128*128; idx+=256){
    int k = idx >> 7, col = idx & 127;
    int h = col >> 5, cc = col & 31;
    int k4 = k>>2, g = k4&3, kk = k4>>3, j = 4*((k4>>2)&1) + (k&3);
    int nb = cc>>4, lane = (cc&15) + 16*g;
    o[(size_t)h*4096 + ((size_t)((kk*2+nb)*64 + lane))*8 + j] = f2b(W[k*128 + col]);
  }
}

// ================= fused CSR build: count+scan+fill in ONE kernel via LDS =================
struct CsrP {
  const int* eg[5];
  int l2E[5];
  int Nd_[5];
  int roff_[5];
  int eoff_[5];
};

__global__ __launch_bounds__(512) void k_csr(CsrP P, int* __restrict__ rowstart,
                                             int* __restrict__ srcidx){
  int b = blockIdx.x, r = blockIdx.y, t = threadIdx.x;
  int E = 1<<P.l2E[r], Nd = P.Nd_[r];
  const int* eg = P.eg[r] + (size_t)b*2*E;
  int* rsO = rowstart + P.roff_[r] + b*(Nd+1);
  int* siO = srcidx + P.eoff_[r] + (size_t)b*E;
  __shared__ int cnt[2048];
  __shared__ int stmp[512];
  for(int i=t;i<Nd;i+=512) cnt[i]=0;
  __syncthreads();
  for(int e=t;e<E;e+=512) atomicAdd(&cnt[eg[E+e]], 1);
  __syncthreads();
  int carry=0;
  for(int c0=0;c0<Nd;c0+=512){
    int idx=c0+t;
    int v=(idx<Nd)?cnt[idx]:0;
    stmp[t]=v; __syncthreads();
    for(int off=1;off<512;off<<=1){
      int u=(t>=off)?stmp[t-off]:0;
      __syncthreads();
      stmp[t]+=u;
      __syncthreads();
    }
    int excl=stmp[t]-v+carry;
    if(idx<Nd){ rsO[idx]=excl; cnt[idx]=excl; }
    int tot = stmp[511];
    __syncthreads();
    carry+=tot;
  }
  if(t==0) rsO[Nd]=carry;
  __syncthreads();
  for(int e=t;e<E;e+=512){
    int src=eg[e], dst=eg[E+e];
    int pos=atomicAdd(&cnt[dst],1);
    siO[pos]=src;
  }
}

// ================= dense hs = x @ W_src per relation (bf16 MFMA) + al_s/al_d epilogues ======
// Block: 256 thr = 4 waves, 16 rows of one (b, type). ct/pet tiles compute 2 W's (self + ->gen).
// Layer 0 stages directly from the fp32 inputs (k_conv deleted).
struct HsP {
  int tb[4];
  int usef;
  const float* xf[3];
  unsigned long long xoff[3];
  int Ns[3];
  int nW[3];
  unsigned long long wfo[3][2];
  unsigned long long hso[3][2];
  unsigned long long aso[3][2];    // als float offsets per rep
  unsigned long long asrco[3][2];  // a_src float offsets per rep (layer-dep)
  int nvd[3];
  unsigned long long vdo[3][3];    // vbuf float offsets (dst vecs, layer-dep)
  unsigned long long aldo2[3][3];  // ald float offsets
  int ndd[3][3];                   // Nd per dst-rel
};

__global__ __launch_bounds__(256) void k_hs(HsP P, const unsigned short* __restrict__ x16,
    const unsigned short* __restrict__ Wf, const float* __restrict__ asrc,
    const float* __restrict__ vbuf, unsigned short* __restrict__ hs,
    float* __restrict__ als, float* __restrict__ ald){
  __shared__ unsigned short xl[16*132];
  int B = blockIdx.x;
  int t=0; while(t<2 && B>=P.tb[t+1]) t++;
  int local = B - P.tb[t];
  int b = local & 31, tile = local >> 5;
  int n0 = tile*16;
  int tid = threadIdx.x, w = tid>>6, ln = tid&63;
  if(P.usef){
    const float* xf = P.xf[t] + ((size_t)((size_t)b*P.Ns[t] + n0))*128;
    int row = tid>>4, c8 = tid&15;
    float4 a = *(const float4*)(xf + (size_t)row*128 + c8*8);
    float4 c = *(const float4*)(xf + (size_t)row*128 + c8*8 + 4);
    u16x8 r;
    r[0]=f2b(a.x); r[1]=f2b(a.y); r[2]=f2b(a.z); r[3]=f2b(a.w);
    r[4]=f2b(c.x); r[5]=f2b(c.y); r[6]=f2b(c.z); r[7]=f2b(c.w);
    *(u16x8*)&xl[row*132 + c8*8] = r;
  } else {
    int row = tid>>4, ch = tid&15;
    u16x8 v = *(const u16x8*)(x16 + P.xoff[t] + ((size_t)((size_t)b*P.Ns[t] + n0+row)*128 + ch*8));
    *(u16x8*)&xl[row*132 + ch*8] = v;
  }
  __syncthreads();
  int g = ln>>4, r15 = ln&15;
  for(int rep=0; rep<P.nW[t]; rep++){
    const unsigned short* wf = Wf + P.wfo[t][rep] + (size_t)w*4096;
    f32x4 acc[2]; acc[0]=(f32x4){0,0,0,0}; acc[1]=(f32x4){0,0,0,0};
    #pragma unroll
    for(int kk=0;kk<4;kk++){
      const unsigned short* pa = &xl[r15*132 + kk*32 + 4*g];
      ushort4 lo = *(const ushort4*)pa;
      ushort4 hi = *(const ushort4*)(pa+16);
      union { ushort u[8]; bf16x8 v; } tmp;
      tmp.u[0]=lo.x; tmp.u[1]=lo.y; tmp.u[2]=lo.z; tmp.u[3]=lo.w;
      tmp.u[4]=hi.x; tmp.u[5]=hi.y; tmp.u[6]=hi.z; tmp.u[7]=hi.w;
      bf16x8 af = tmp.v;
      #pragma unroll
      for(int nb=0;nb<2;nb++){
        bf16x8 bw = *(const bf16x8*)(wf + ((size_t)((kk*2+nb)*64 + ln))*8);
        acc[nb] = __builtin_amdgcn_mfma_f32_16x16x32_bf16(af, bw, acc[nb], 0, 0, 0);
      }
    }
    unsigned short* ho = hs + P.hso[t][rep] + ((size_t)b*P.Ns[t] + n0)*128;
    #pragma unroll
    for(int qq=0;qq<4;qq++){
      int m = 4*g + qq;
      #pragma unroll
      for(int nb=0;nb<2;nb++){
        ho[(size_t)m*128 + w*32 + nb*16 + r15] = f2b(acc[nb][qq]);
      }
    }
    // ---- al_s epilogue: reduce acc over cols of head w ----
    {
      const float* aS = asrc + P.asrco[t][rep];
      float a0v = aS[w*32 + r15], a1v = aS[w*32 + 16 + r15];
      float p0 = acc[0][0]*a0v + acc[1][0]*a1v;
      float p1 = acc[0][1]*a0v + acc[1][1]*a1v;
      float p2 = acc[0][2]*a0v + acc[1][2]*a1v;
      float p3 = acc[0][3]*a0v + acc[1][3]*a1v;
      #pragma unroll
      for(int off=1; off<16; off<<=1){
        p0 += __shfl_xor(p0,off); p1 += __shfl_xor(p1,off);
        p2 += __shfl_xor(p2,off); p3 += __shfl_xor(p3,off);
      }
      if(r15 < 4){
        float pv = (r15==0)?p0:((r15==1)?p1:((r15==2)?p2:p3));
        als[P.aso[t][rep] + ((size_t)b*P.Ns[t] + n0 + 4*g + r15)*4 + w] = pv;
      }
    }
  }
  // ---- al_d: x-tile (LDS) dot folded dst vectors ----
  int nvd = P.nvd[t];
  if(tid < (nvd<<6)){
    int vd = tid>>6, rem = tid&63, row = rem>>2, h = rem&3;
    const float* vv = vbuf + P.vdo[t][vd];
    float s = 0.f;
    #pragma unroll 8
    for(int k=0;k<128;k++) s += b2f(xl[row*132+k]) * vv[k*4+h];
    ald[P.aldo2[t][vd] + ((size_t)b*P.ndd[t][vd] + n0 + row)*4 + h] = s;
  }
}

// ========= fused softmax + gather, 64-dst tiles, XCD-local b, baked combined edges =========
// Key invariant: als float-offset/4 == hs row-offset per relation (both are prefix sums of
// B*Ns), so ONE baked index sil gives als+4*sil (pass1) and hs+128*sil (pass3).
static constexpr int MAXE4 = 1536;  // combined edge cap: gen mean 1024, sigma ~32 -> +16 sigma
static constexpr int WST4  = 1548;  // head-major wlds stride (mult of 4 for b128; mod 32 = 12)

struct Fu5P {
  int nrel[3], ndshift[3];
  int roff[3][3], eoff[3][3], E[3][3], Ns[3][3];
  int rowbase[3][3];
  unsigned long long aldo[3][3];
  unsigned long long outoff[3];
};

__global__ __launch_bounds__(512, 8) void k_fuse5(Fu5P P,
    const int* __restrict__ rowstart, const int* __restrict__ srcidx,
    const float* __restrict__ als, const float* __restrict__ ald,
    const unsigned short* __restrict__ hs, unsigned short* __restrict__ out16){
  __shared__ float wlds[4*WST4];   // 24.8 KB
  __shared__ int   silds[MAXE4];   // 6 KB
  __shared__ float aldl[3*256];    // 3 KB
  __shared__ int   rsl[3*65];
  __shared__ int   crs[65];
  __shared__ int   cst[3*64];
  // XCD-locality decode: blocks with B%8==x all share b%8==x -> each XCD's L2 holds
  // only 4 b's worth of hs/als slices (~3 MB) instead of all 32 (~32 MB).
  int B = blockIdx.x;
  int xcd = B & 7, slot = B >> 3;
  int bg = slot >> 6, rem = slot & 63;
  int b = bg*8 + xcd;
  int t, dtile;
  if(rem < 32){ t = 0; dtile = rem; }
  else if(rem < 48){ t = 1; dtile = rem - 32; }
  else { t = 2; dtile = rem - 48; }
  int Nd = 1 << P.ndshift[t];
  int d0 = dtile * 64;
  int tid = threadIdx.x, w = tid>>6, ln = tid&63;
  int nrel = P.nrel[t];

  // ---- phase0a: stage rs rows + ald ----
  for(int q=0;q<nrel;q++){
    const int* rsq = rowstart + P.roff[t][q] + b*(Nd+1) + d0;
    for(int i=tid;i<65;i+=512) rsl[q*65+i] = rsq[i];
    const float* aldq = ald + P.aldo[t][q] + ((size_t)b*Nd + d0)*4;
    for(int i=tid;i<256;i+=512) aldl[(q<<8)+i] = aldq[i];
  }
  __syncthreads();
  // ---- phase0b: combined-segment offsets (crs) + per-(rel,dst) starts (cst) ----
  if(tid < 65){
    int s = 0;
    for(int q=0;q<nrel;q++) s += rsl[q*65+tid] - rsl[q*65];
    crs[tid] = s;
  } else if(tid >= 128 && tid < 128 + nrel*64){
    int q = (tid-128)>>6, d = (tid-128)&63;
    int s = 0;
    for(int q2=0;q2<nrel;q2++) s += rsl[q2*65+d] - rsl[q2*65];
    for(int q2=0;q2<q;q2++)    s += rsl[q2*65+d+1] - rsl[q2*65+d];
    cst[q*64+d] = s;
  }
  __syncthreads();
  // ---- phase0c: scatter src indices into per-dst combined segments, baked ----
  for(int s=tid; s<(nrel<<8); s+=512){
    int q = s>>8, r2 = s&255, dloc = r2>>2, j = r2&3;
    const int* si = srcidx + P.eoff[t][q] + (size_t)b*P.E[t][q];
    int rs0 = rsl[q*65+dloc];
    int deg = rsl[q*65+dloc+1] - rs0;
    int cb = cst[q*64+dloc];
    int bake = P.rowbase[t][q] + b*P.Ns[t][q];
    for(int i=j;i<deg;i+=4) silds[cb+i] = bake + si[rs0+i];
  }
  __syncthreads();
  // ---- pass1: logits, 1 float4 als gather per edge (L2-local), ald from LDS ----
  for(int s=tid; s<(nrel<<8); s+=512){
    int q = s>>8, r2 = s&255, dloc = r2>>2, j = r2&3;
    int deg = rsl[q*65+dloc+1] - rsl[q*65+dloc];
    int cb = cst[q*64+dloc];
    float4 ad4 = *(const float4*)&aldl[(q<<8)+(dloc<<2)];
    for(int i=j;i<deg;i+=4){
      int e = cb+i;
      int sil = silds[e];
      float4 as4 = *(const float4*)(als + 4*(size_t)sil);
      wlds[0*WST4+e] = lrelu(as4.x+ad4.x);
      wlds[1*WST4+e] = lrelu(as4.y+ad4.y);
      wlds[2*WST4+e] = lrelu(as4.z+ad4.z);
      wlds[3*WST4+e] = lrelu(as4.w+ad4.w);
    }
  }
  __syncthreads();
  // ---- pass2: segmented softmax per (rel,dst,head), LDS only ----
  for(int s=tid; s<(nrel<<8); s+=512){
    int q = s>>8, r2 = s&255, dloc = r2>>2, h2 = r2&3;
    int e0 = cst[q*64+dloc];
    int e1 = e0 + rsl[q*65+dloc+1] - rsl[q*65+dloc];
    float* wrow = &wlds[h2*WST4];
    float m = -1e30f;
    for(int e=e0;e<e1;e++) m = fmaxf(m, wrow[e]);
    float den = 0.f;
    for(int e=e0;e<e1;e++){ float p=__expf(wrow[e]-m); wrow[e]=p; den+=p; }
    float inv = 1.f/(den + 1e-16f);
    for(int e=e0;e<e1;e++) wrow[e] *= inv;
  }
  __syncthreads();
  // ---- pass3: weighted gather over combined segments, 8 dsts/wave, 8-deep unroll ----
  int h = ln>>4;
  float accA[8], accB[8];
  #pragma unroll
  for(int i=0;i<8;i++){ accA[i]=0.f; accB[i]=0.f; }
  #pragma unroll
  for(int it=0; it<8; it++){
    int dloc = w*8 + it;
    int e0 = crs[dloc], e1 = crs[dloc+1];
    float a0 = 0.f, a1 = 0.f;
    int e = e0;
    int eal = (e0+3)&~3; if(eal > e1) eal = e1;
    for(; e<eal; e++){
      float wv = wlds[h*WST4 + e];
      unsigned v = *(const unsigned*)(hs + ((size_t)silds[e]*128 + 2*ln));
      a0 += wv*__uint_as_float(v<<16);
      a1 += wv*__uint_as_float(v&0xFFFF0000u);
    }
    for(; e+8<=e1; e+=8){
      int4  sq0 = *(const int4*)&silds[e];
      int4  sq1 = *(const int4*)&silds[e+4];
      float4 wq0 = *(const float4*)&wlds[h*WST4 + e];
      float4 wq1 = *(const float4*)&wlds[h*WST4 + e + 4];
      unsigned v0 = *(const unsigned*)(hs + ((size_t)sq0.x*128 + 2*ln));
      unsigned v1 = *(const unsigned*)(hs + ((size_t)sq0.y*128 + 2*ln));
      unsigned v2 = *(const unsigned*)(hs + ((size_t)sq0.z*128 + 2*ln));
      unsigned v3 = *(const unsigned*)(hs + ((size_t)sq0.w*128 + 2*ln));
      unsigned v4 = *(const unsigned*)(hs + ((size_t)sq1.x*128 + 2*ln));
      unsigned v5 = *(const unsigned*)(hs + ((size_t)sq1.y*128 + 2*ln));
      unsigned v6 = *(const unsigned*)(hs + ((size_t)sq1.z*128 + 2*ln));
      unsigned v7 = *(const unsigned*)(hs + ((size_t)sq1.w*128 + 2*ln));
      a0 += wq0.x*__uint_as_float(v0<<16); a1 += wq0.x*__uint_as_float(v0&0xFFFF0000u);
      a0 += wq0.y*__uint_as_float(v1<<16); a1 += wq0.y*__uint_as_float(v1&0xFFFF0000u);
      a0 += wq0.z*__uint_as_float(v2<<16); a1 += wq0.z*__uint_as_float(v2&0xFFFF0000u);
      a0 += wq0.w*__uint_as_float(v3<<16); a1 += wq0.w*__uint_as_float(v3&0xFFFF0000u);
      a0 += wq1.x*__uint_as_float(v4<<16); a1 += wq1.x*__uint_as_float(v4&0xFFFF0000u);
      a0 += wq1.y*__uint_as_float(v5<<16); a1 += wq1.y*__uint_as_float(v5&0xFFFF0000u);
      a0 += wq1.z*__uint_as_float(v6<<16); a1 += wq1.z*__uint_as_float(v6&0xFFFF0000u);
      a0 += wq1.w*__uint_as_float(v7<<16); a1 += wq1.w*__uint_as_float(v7&0xFFFF0000u);
    }
    for(; e+4<=e1; e+=4){
      int4  sq = *(const int4*)&silds[e];
      float4 wq = *(const float4*)&wlds[h*WST4 + e];
      unsigned v0 = *(const unsigned*)(hs + ((size_t)sq.x*128 + 2*ln));
      unsigned v1 = *(const unsigned*)(hs + ((size_t)sq.y*128 + 2*ln));
      unsigned v2 = *(const unsigned*)(hs + ((size_t)sq.z*128 + 2*ln));
      unsigned v3 = *(const unsigned*)(hs + ((size_t)sq.w*128 + 2*ln));
      a0 += wq.x*__uint_as_float(v0<<16); a1 += wq.x*__uint_as_float(v0&0xFFFF0000u);
      a0 += wq.y*__uint_as_float(v1<<16); a1 += wq.y*__uint_as_float(v1&0xFFFF0000u);
      a0 += wq.z*__uint_as_float(v2<<16); a1 += wq.z*__uint_as_float(v2&0xFFFF0000u);
      a0 += wq.w*__uint_as_float(v3<<16); a1 += wq.w*__uint_as_float(v3&0xFFFF0000u);
    }
    for(; e<e1; e++){
      float wv = wlds[h*WST4 + e];
      unsigned v = *(const unsigned*)(hs + ((size_t)silds[e]*128 + 2*ln));
      a0 += wv*__uint_as_float(v<<16);
      a1 += wv*__uint_as_float(v&0xFFFF0000u);
    }
    accA[it] = a0; accB[it] = a1;
  }
  // ---- epilogue: ELU + bf16 store ----
  #pragma unroll
  for(int it=0; it<8; it++){
    int m = d0 + w*8 + it;
    float v0 = accA[it], v1 = accB[it];
    v0 = v0 > 0.f ? v0 : expm1f(v0);
    v1 = v1 > 0.f ? v1 : expm1f(v1);
    ushort2 o; o.x = f2b(v0); o.y = f2b(v1);
    *(ushort2*)(out16 + P.outoff[t] + ((size_t)b*Nd + m)*128 + 2*ln) = o;
  }
}

// ================= pooling (3 pools batched via blockIdx.z; bf16 features) =================
__device__ __constant__ const size_t POFF[3] = {0ull, 4194304ull, 8388608ull};
__device__ __constant__ const int    PNN[3]  = {1024, 1024, 2048};
static constexpr int PCH = 64;
static constexpr int MAXCH = 32;

__global__ __launch_bounds__(128) void k_pool_psum(const unsigned short* __restrict__ x2,
    float* __restrict__ part){
  int p = blockIdx.z, b = blockIdx.x, c = blockIdx.y, t = threadIdx.x;
  int Nn = PNN[p];
  if(c*PCH >= Nn) return;
  const unsigned short* f = x2 + POFF[p] + ((size_t)b*Nn + c*PCH)*ND;
  float acc = 0.f;
  #pragma unroll 8
  for(int n=0;n<PCH;n++) acc += b2f(f[(size_t)n*ND + t]);
  part[(((size_t)p*NB + b)*MAXCH + c)*ND + t] = acc;
}

__global__ __launch_bounds__(128) void k_pool_q(const float* __restrict__ part,
    const float* __restrict__ Wp, const float* __restrict__ bp,
    float* __restrict__ q){
  int p = blockIdx.z, b = blockIdx.x, t = threadIdx.x;
  int nch = PNN[p]/PCH;
  __shared__ float mean[ND];
  float s = 0.f;
  for(int c=0;c<nch;c++) s += part[(((size_t)p*NB + b)*MAXCH + c)*ND + t];
  mean[t] = s / (float)PNN[p];
  __syncthreads();
  const float* W = Wp + (size_t)p*ND*ND;
  float qv = bp[p*ND + t];
  #pragma unroll 8
  for(int k=0;k<ND;k++) qv += mean[k]*W[k*ND + t];
  q[((size_t)p*NB + b)*ND + t] = qv;
}

__global__ __launch_bounds__(256) void k_pool_score(const unsigned short* __restrict__ x2,
    const float* __restrict__ q, float* __restrict__ sc){
  int p = blockIdx.z, b = blockIdx.y;
  int w = threadIdx.x >> 6, lane = threadIdx.x & 63;
  int n = blockIdx.x*4 + w;
  int Nn = PNN[p];
  if(n >= Nn) return;
  const unsigned short* f  = x2 + POFF[p] + ((size_t)b*Nn + n)*ND;
  const float* qb = q + ((size_t)p*NB + b)*ND;
  float s = b2f(f[lane])*qb[lane] + b2f(f[lane+64])*qb[lane+64];
  #pragma unroll
  for(int off=32; off; off>>=1) s += __shfl_xor(s, off);
  if(lane == 0) sc[((size_t)p*NB + b)*2048 + n] = s;
}

__global__ __launch_bounds__(256) void k_pool_smax(const float* __restrict__ sc,
    float* __restrict__ stat){
  int p = blockIdx.z, b = blockIdx.x, t = threadIdx.x;
  int Nn = PNN[p];
  __shared__ float red[256];
  const float* s = sc + ((size_t)p*NB + b)*2048;
  float mx = -1e30f;
  for(int n=t;n<Nn;n+=256) mx = fmaxf(mx, s[n]);
  red[t] = mx; __syncthreads();
  for(int o=128;o;o>>=1){ if(t<o) red[t]=fmaxf(red[t],red[t+o]); __syncthreads(); }
  mx = red[0]; __syncthreads();
  float sum = 0.f;
  for(int n=t;n<Nn;n+=256) sum += __expf(s[n]-mx);
  red[t] = sum; __syncthreads();
  for(int o=128;o;o>>=1){ if(t<o) red[t]+=red[t+o]; __syncthreads(); }
  if(t==0){ stat[((size_t)p*NB + b)*2] = mx; stat[((size_t)p*NB + b)*2+1] = 1.f/red[0]; }
}

__global__ __launch_bounds__(128) void k_pool_wsum(const unsigned short* __restrict__ x2,
    const float* __restrict__ sc, const float* __restrict__ stat,
    float* __restrict__ part){
  int p = blockIdx.z, b = blockIdx.x, c = blockIdx.y, t = threadIdx.x;
  int Nn = PNN[p];
  if(c*PCH >= Nn) return;
  __shared__ float wsh[PCH];
  float mx  = stat[((size_t)p*NB + b)*2];
  float inv = stat[((size_t)p*NB + b)*2+1];
  if(t < PCH) wsh[t] = __expf(sc[((size_t)p*NB + b)*2048 + c*PCH + t] - mx)*inv;
  __syncthreads();
  const unsigned short* f = x2 + POFF[p] + ((size_t)b*Nn + c*PCH)*ND;
  float acc = 0.f;
  #pragma unroll 8
  for(int n=0;n<PCH;n++) acc += wsh[n]*b2f(f[(size_t)n*ND + t]);
  part[(((size_t)p*NB + b)*MAXCH + c)*ND + t] = acc;
}

__global__ __launch_bounds__(128) void k_pool_comb(const float* __restrict__ part,
    float* __restrict__ pooled){
  int p = blockIdx.z, b = blockIdx.x, t = threadIdx.x;
  int nch = PNN[p]/PCH;
  float s = 0.f;
  for(int c=0;c<nch;c++) s += part[(((size_t)p*NB + b)*MAXCH + c)*ND + t];
  pooled[((size_t)p*NB + b)*ND + t] = s;
}

// ---- semantic attention + fuse ----
__global__ __launch_bounds__(128) void k_sem(const float* __restrict__ ctp,
    const float* __restrict__ petp, const float* __restrict__ genp,
    const float* __restrict__ Wsem, const float* __restrict__ bsem,
    const float* __restrict__ qsem, float* __restrict__ fused, float* __restrict__ beta){
  int b = blockIdx.x, t = threadIdx.x;
  __shared__ float z[3][256];
  __shared__ float red[128];
  float ct = ctp[b*ND + t], pet = petp[b*ND + t], gen = genp[b*ND + t];
  z[0][t]=ct;  z[1][t]=pet; z[2][t]=0.5f*(ct+pet);
  z[0][ND+t]=gen; z[1][ND+t]=gen; z[2][ND+t]=gen;
  __syncthreads();
  float s[3];
  for(int p=0;p<3;p++){
    float a = bsem[t];
    for(int f=0;f<256;f++) a += z[p][f]*Wsem[f*128 + t];
    a = tanhf(a);
    red[t] = a * qsem[t];
    __syncthreads();
    for(int o=64;o>0;o>>=1){ if(t<o) red[t]+=red[t+o]; __syncthreads(); }
    s[p] = red[0]; __syncthreads();
  }
  float mx = fmaxf(s[0], fmaxf(s[1], s[2]));
  float e0 = __expf(s[0]-mx), e1 = __expf(s[1]-mx), e2 = __expf(s[2]-mx);
  float sm = e0+e1+e2;
  float b0 = e0/sm, b1 = e1/sm, b2 = e2/sm;
  if(t < 3) beta[b*3 + t] = (t==0)?b0:((t==1)?b1:b2);
  float f0 = b0*z[0][t] + b1*z[1][t] + b2*z[2][t];
  float f1 = b0*z[0][ND+t] + b1*z[1][ND+t] + b2*z[2][ND+t];
  fused[(size_t)b*512 + t]       = f0;
  fused[(size_t)b*512 + 128 + t] = f1;
  fused[(size_t)b*512 + 256 + t] = 0.f;
  fused[(size_t)b*512 + 384 + t] = 0.f;
}

extern "C" void kernel_launch(void* const* d_in, const int* in_sizes, int n_in,
                              void* d_out, int out_size, void* d_ws, size_t ws_size,
                              hipStream_t stream) {
  // live relations lr0..4 = orig {r0 ct>ct, r1 pet>pet, r3 gen>gen, r5 ct>gen, r6 pet>gen}
  static const int wid[5]    = {0,1,3,5,6};
  static const int edgein[5] = {5,6,8,10,11};
  static const int l2E[5]    = {13,13,14,13,13};
  static const int Nd_l[5]   = {1024,1024,2048,2048,2048};
  static const int E_l[5]    = {8192,8192,16384,8192,8192};
  static const int Ns_l[5]   = {1024,1024,2048,1024,1024};
  static const int eoff[6]   = {0,262144,524288,1048576,1310720,1572864};
  static const int roff[5]   = {0,32800,65600,131168,196736};
  static const unsigned long long aoff[5]   = {0,131072,262144,524288,655360};
  static const unsigned long long aldoff[5] = {0,131072,262144,524288,786432};
  static const unsigned long long hsoff_lr[5] = {0ull,4194304ull,8388608ull,16777216ull,20971520ull};
  static const unsigned long long ALD = 786432;

  const float* Wsrc = (const float*)d_in[13];
  const float* Wp   = (const float*)d_in[17];
  const float* bp   = (const float*)d_in[18];
  const float* Wsem = (const float*)d_in[19];
  const float* bsem = (const float*)d_in[20];
  const float* qsem = (const float*)d_in[21];

  unsigned short* xc16 = (unsigned short*)d_ws;               // layer-1 out (final features)
  unsigned short* x2b16 = xc16;                               // alias
  unsigned short* xmid16 = xc16 + 16777216;                   // layer-0 out / layer-1 in
  float* albase = (float*)(xmid16 + 16777216);                // 1,835,008 f
  float* als = albase;
  float* ald = albase + ALD;
  float* vbuf = albase + 1835008;                             // 10,240 f
  unsigned short* wfbuf = (unsigned short*)(vbuf + 10240);    // 163,840 us
  float* pooled = (float*)(wfbuf + 163840);                   // 12,288
  float* part = pooled + 12288;                               // 393,216
  float* qbuf = part + 393216;                                // 12,288
  float* scbuf = qbuf + 12288;                                // 196,608
  float* stat = scbuf + 196608;                               // 192
  int* rowstart = (int*)(stat + 192);                         // 262,304
  int* srcidx = rowstart + 262304;                            // 1,572,864
  unsigned short* hs16 = (unsigned short*)(srcidx + 1572864); // 25,165,824 us (50.3 MB)

  // ---- fold attention vectors + pre-pack W fragments ----
  { dim3 g(5,2,2); k_fold<<<g,128,0,stream>>>(Wsrc, (const float*)d_in[14],
                                              (const float*)d_in[15], (const float*)d_in[16], vbuf); }
  { dim3 g(5,2); k_wpack<<<g,256,0,stream>>>(Wsrc, wfbuf); }

  // ---- fused CSR build ----
  CsrP csr;
  for(int r=0;r<5;r++){
    csr.eg[r] = (const int*)d_in[edgein[r]];
    csr.l2E[r] = l2E[r]; csr.Nd_[r] = Nd_l[r];
    csr.roff_[r] = roff[r]; csr.eoff_[r] = eoff[r];
  }
  { dim3 g(NB,5); k_csr<<<g,512,0,stream>>>(csr, rowstart, srcidx); }

  static const unsigned long long xoo[3] = {0,4194304,8388608};
  // fused-kernel type order: 0=gen (3 rels), 1=ct, 2=pet
  static const int t2_nrel[3] = {3,1,1};
  static const int t2_lrel[3][3] = {{2,3,4},{0,0,0},{1,0,0}};
  static const int t2_nds[3] = {11,10,10};
  static const int t2_out[3] = {2,0,1};

  Fu5P fp;
  for(int t=0;t<3;t++){
    fp.nrel[t]=t2_nrel[t]; fp.ndshift[t]=t2_nds[t]; fp.outoff[t]=xoo[t2_out[t]];
    for(int q=0;q<3;q++){
      int lr = t2_lrel[t][q];
      fp.roff[t][q]=roff[lr]; fp.eoff[t][q]=eoff[lr];
      fp.E[t][q]=E_l[lr]; fp.Ns[t][q]=Ns_l[lr];
      fp.rowbase[t][q]=(int)(aoff[lr]/4);   // == hs row base (same prefix sums)
      fp.aldo[t][q]=aldoff[lr];
    }
  }

  // k_hs grid decode: type order 0=ct, 1=pet, 2=gen; reps per (t): ct{lr0,lr3}, pet{lr1,lr4}, gen{lr2}
  static const int hs_lr[3][2] = {{0,3},{1,4},{2,2}};
  static const int vd_lr[3][3] = {{0,0,0},{1,0,0},{2,3,4}};
  HsP hp;
  hp.tb[0]=0; hp.tb[1]=2048; hp.tb[2]=4096; hp.tb[3]=8192;
  hp.xf[0]=(const float*)d_in[0]; hp.xf[1]=(const float*)d_in[1]; hp.xf[2]=(const float*)d_in[3];
  hp.xoff[0]=0; hp.xoff[1]=4194304; hp.xoff[2]=8388608;
  hp.Ns[0]=1024; hp.Ns[1]=1024; hp.Ns[2]=2048;
  hp.nW[0]=2; hp.nW[1]=2; hp.nW[2]=1;
  hp.nvd[0]=1; hp.nvd[1]=1; hp.nvd[2]=3;
  for(int t=0;t<3;t++){
    for(int rep=0;rep<2;rep++){
      int lr = hs_lr[t][rep];
      hp.hso[t][rep]=hsoff_lr[lr];
      hp.aso[t][rep]=aoff[lr];
    }
    for(int vd=0;vd<3;vd++){
      int lr = vd_lr[t][vd];
      hp.aldo2[t][vd]=aldoff[lr];
      hp.ndd[t][vd]=Nd_l[lr];
    }
  }
  hp.hso[2][1]=0; hp.aso[2][1]=0;

  for(int l=0;l<2;l++){
    unsigned short* xout = (l==0) ? xmid16 : x2b16;
    hp.usef = (l==0) ? 1 : 0;

    for(int t=0;t<3;t++){
      for(int rep=0;rep<2;rep++){
        int lr = hs_lr[t][rep];
        hp.wfo[t][rep]=(unsigned long long)((l*5 + lr)*4)*4096;
        hp.asrco[t][rep]=(unsigned long long)((l*8 + wid[lr])*128);
      }
      for(int vd=0;vd<3;vd++){
        int lr = vd_lr[t][vd];
        hp.vdo[t][vd]=((unsigned long long)((l*5+lr)*2+1))*512;
      }
    }
    k_hs<<<8192,256,0,stream>>>(hp, xmid16, wfbuf, (const float*)d_in[15], vbuf,
                                hs16, als, ald);

    k_fuse5<<<2048,512,0,stream>>>(fp, rowstart, srcidx, als, ald, hs16, xout);
  }

  // ---- pooling (bf16 features) ----
  {
    dim3 gchunk(NB, MAXCH, 3);
    dim3 gone(NB, 1, 3);
    dim3 gscore(512, NB, 3);
    k_pool_psum <<<gchunk,128,0,stream>>>(x2b16, part);
    k_pool_q    <<<gone,  128,0,stream>>>(part, Wp, bp, qbuf);
    k_pool_score<<<gscore,256,0,stream>>>(x2b16, qbuf, scbuf);
    k_pool_smax <<<gone,  256,0,stream>>>(scbuf, stat);
    k_pool_wsum <<<gchunk,128,0,stream>>>(x2b16, scbuf, stat, part);
    k_pool_comb <<<gone,  128,0,stream>>>(part, pooled);
  }

  float* fused = (float*)d_out;
  float* beta  = fused + (size_t)NB*512;
  k_sem<<<NB,128,0,stream>>>(pooled, pooled + NB*ND, pooled + 2*NB*ND,
                             Wsem, bsem, qsem, fused, beta);
}